// Round 1
// 814.163 us; speedup vs baseline: 3.9363x; 3.9363x over previous
//
#include <hip/hip_runtime.h>
#include <stdint.h>

#define NEG_SLOPE 0.2f
#define SEPS 1e-16f

static __device__ __forceinline__ float bf2f(ushort u) {
  union { uint32_t i; float f; } v; v.i = ((uint32_t)u) << 16; return v.f;
}
static __device__ __forceinline__ ushort f2bf(float f) {
  uint32_t b = __float_as_uint(f);
  b += 0x7FFFu + ((b >> 16) & 1u);      // RNE
  return (ushort)(b >> 16);
}
static __device__ __forceinline__ float ldf(const void* p, size_t i, int mode) {
  return mode ? ((const float*)p)[i] : bf2f(((const ushort*)p)[i]);
}
static __device__ __forceinline__ void atomicMaxCAS(float* a, float v) {
  int* ai = (int*)a;
  int old = __float_as_int(*a);
  while (__int_as_float(old) < v) {
    int assumed = old;
    old = atomicCAS(ai, assumed, __float_as_int(v));
    if (old == assumed) break;
  }
}

// ---------------- fills ----------------
__global__ void fill_out(float* __restrict__ out, int n, float v) {
  int i = blockIdx.x * 256 + threadIdx.x;
  if (i < n) out[i] = v;
}
__global__ void fill_f32(float* __restrict__ p, int n, float v) {
  int i = blockIdx.x * 256 + threadIdx.x;
  if (i < n) p[i] = v;
}
__global__ void fill_i32(int* __restrict__ p, int n, int v) {
  int i = blockIdx.x * 256 + threadIdx.x;
  if (i < n) p[i] = v;
}

// ---------------- storage detectors (proven R5-R11) ----------------
__global__ void detect_store(const uint32_t* __restrict__ w, int elems,
                             int* __restrict__ mode) {
  __shared__ int sL, sH;
  if (threadIdx.x == 0) { sL = 0; sH = 0; }
  __syncthreads();
  int nprobe = min(2048, elems / 2);
  int cL = 0, cH = 0;
  for (int i = threadIdx.x; i < nprobe; i += 256) {
    uint32_t v = w[i];
    uint32_t eL = (v >> 7) & 0xFFu;
    uint32_t eH = (v >> 23) & 0xFFu;
    if (eL >= 90u && eL <= 128u) cL++;
    if (eH >= 90u && eH <= 128u) cH++;
  }
  atomicAdd(&sL, cL); atomicAdd(&sH, cH);
  __syncthreads();
  if (threadIdx.x == 0) {
    int m;
    if (sL * 4 >= nprobe * 3) m = 0;
    else if (sH * 4 >= nprobe) m = 1;
    else m = 0;
    *mode = m;
  }
}
__global__ void detect_i64(const uint32_t* __restrict__ w, int elems,
                           int* __restrict__ mode) {
  __shared__ int sz;
  if (threadIdx.x == 0) sz = 0;
  __syncthreads();
  int nprobe = min(4096, elems);
  int c = 0;
  for (int i = threadIdx.x; i < nprobe; i += 256)
    if ((i & 1) && w[i] == 0u) c++;
  atomicAdd(&sz, c);
  __syncthreads();
  if (threadIdx.x == 0) *mode = (sz * 4 >= (nprobe / 2) * 3) ? 1 : 0;
}

// ---------------- canonicalizers ----------------
__global__ void canon_idx(const void* __restrict__ ei, int* __restrict__ srcc,
                          int* __restrict__ dstc, int E, int N,
                          const int* __restrict__ m64) {
  int i = blockIdx.x * 256 + threadIdx.x;
  if (i >= E) return;
  int s, d;
  if (*m64) {
    s = (int)((const long long*)ei)[i];
    d = (int)((const long long*)ei)[E + i];
  } else {
    s = ((const int*)ei)[i];
    d = ((const int*)ei)[E + i];
  }
  srcc[i] = min(max(s, 0), N - 1);
  dstc[i] = min(max(d, 0), N - 1);
}
__global__ void canon_f32(const void* __restrict__ in, float* __restrict__ out,
                          int n, const int* __restrict__ mode) {
  int i = blockIdx.x * 256 + threadIdx.x;
  if (i >= n) return;
  float v = ldf(in, i, *mode);
  if (!isfinite(v)) v = 0.f;
  out[i] = v;
}

// ---------------- CSR build (proven R1-R7) ----------------
__global__ void count_deg(const int* __restrict__ dstv, int* __restrict__ deg, int E) {
  int e = blockIdx.x * 256 + threadIdx.x;
  if (e < E) atomicAdd(&deg[dstv[e]], 1);
}
__global__ __launch_bounds__(1024) void scan_deg(const int* __restrict__ deg,
                                                 int* __restrict__ row_ptr,
                                                 int* __restrict__ row_cur, int N) {
  __shared__ int part[1024];
  int t = threadIdx.x;
  int chunk = (N + 1023) / 1024;
  int lo = t * chunk, hi = min(lo + chunk, N);
  int s = 0;
  for (int i = lo; i < hi; ++i) s += deg[i];
  part[t] = s;
  __syncthreads();
  for (int off = 1; off < 1024; off <<= 1) {
    int v = (t >= off) ? part[t - off] : 0;
    __syncthreads();
    part[t] += v;
    __syncthreads();
  }
  int base = (t == 0) ? 0 : part[t - 1];
  for (int i = lo; i < hi; ++i) {
    row_ptr[i] = base; row_cur[i] = base;
    base += deg[i];
  }
  if (t == 1023) row_ptr[N] = part[1023];
}
__global__ void scatter_edges(const int* __restrict__ dstv, int* __restrict__ row_cur,
                              int* __restrict__ csr_e, int E) {
  int e = blockIdx.x * 256 + threadIdx.x;
  if (e < E) {
    int p = atomicAdd(&row_cur[dstv[e]], 1);
    csr_e[p] = e;
  }
}

// ---------------- tiled GEMM: out_bf16[M,BN] = A[M,K] @ W[K,BN] -----------
// A is fp32 or bf16 (runtime mode; modeA==nullptr -> fp32).
// W is fp32 in natural [K][BN] row-major layout (coalesced staging).
// 256 threads; tile BM=32 x BN; BK=32; per-thread TM rows x 4 cols.
template <int BN>
__global__ __launch_bounds__(256) void gemm_tiled(
    const void* __restrict__ A, const float* __restrict__ W,
    ushort* __restrict__ out, int M, int K,
    const int* __restrict__ modeA) {
  constexpr int BM = 32;
  constexpr int BK = 32;
  constexpr int CG = BN / 4;        // column groups (64 or 32)
  constexpr int RG = 256 / CG;      // row groups (4 or 8)
  constexpr int TM = BM / RG;       // rows per thread (8 or 4)
  __shared__ float Xs[BM][BK + 4];  // +4 pad keeps float4 alignment (144B rows)
  __shared__ float Ws[BK][BN];

  int t = threadIdx.x;
  int m0 = blockIdx.x * BM;
  int tc = t % CG;                  // cols 4*tc .. 4*tc+3
  int tr = t / CG;                  // rows TM*tr .. TM*tr+TM-1

  float acc[TM][4];
#pragma unroll
  for (int i = 0; i < TM; ++i) { acc[i][0] = acc[i][1] = acc[i][2] = acc[i][3] = 0.f; }

  int mode = modeA ? *modeA : 1;

  // staging indices for X: 1024 floats, 4 per thread
  int sxm = t >> 3;                 // row within tile (0..31)
  int sxk = (t & 7) * 4;            // k offset within tile
  int srow = min(m0 + sxm, M - 1);  // clamped (safe duplicate reads)

  for (int k0 = 0; k0 < K; k0 += BK) {
    // ---- stage X tile ----
    if (mode) {
      const float4 v = *(const float4*)((const float*)A + (size_t)srow * K + k0 + sxk);
      Xs[sxm][sxk + 0] = v.x; Xs[sxm][sxk + 1] = v.y;
      Xs[sxm][sxk + 2] = v.z; Xs[sxm][sxk + 3] = v.w;
    } else {
      const ushort4 v = *(const ushort4*)((const ushort*)A + (size_t)srow * K + k0 + sxk);
      Xs[sxm][sxk + 0] = bf2f(v.x); Xs[sxm][sxk + 1] = bf2f(v.y);
      Xs[sxm][sxk + 2] = bf2f(v.z); Xs[sxm][sxk + 3] = bf2f(v.w);
    }
    // ---- stage W tile (coalesced float4, natural layout) ----
    constexpr int PER = (BK * BN) / 1024;     // float4 per thread (8 or 4)
#pragma unroll
    for (int i = 0; i < PER; ++i) {
      int f = t + i * 256;                    // float4 index
      int kk = (f * 4) / BN;
      int nn = (f * 4) % BN;
      *(float4*)&Ws[kk][nn] = *(const float4*)&W[(size_t)(k0 + kk) * BN + nn];
    }
    __syncthreads();

    // ---- compute: k unrolled by 4, float4 LDS reads ----
#pragma unroll
    for (int k4 = 0; k4 < BK; k4 += 4) {
      float4 xv[TM];
#pragma unroll
      for (int i = 0; i < TM; ++i)
        xv[i] = *(const float4*)&Xs[tr * TM + i][k4];   // wave-broadcast reads
      float4 w0 = *(const float4*)&Ws[k4 + 0][tc * 4];
      float4 w1 = *(const float4*)&Ws[k4 + 1][tc * 4];
      float4 w2 = *(const float4*)&Ws[k4 + 2][tc * 4];
      float4 w3 = *(const float4*)&Ws[k4 + 3][tc * 4];
#pragma unroll
      for (int i = 0; i < TM; ++i) {
        acc[i][0] += xv[i].x * w0.x; acc[i][1] += xv[i].x * w0.y;
        acc[i][2] += xv[i].x * w0.z; acc[i][3] += xv[i].x * w0.w;
        acc[i][0] += xv[i].y * w1.x; acc[i][1] += xv[i].y * w1.y;
        acc[i][2] += xv[i].y * w1.z; acc[i][3] += xv[i].y * w1.w;
        acc[i][0] += xv[i].z * w2.x; acc[i][1] += xv[i].z * w2.y;
        acc[i][2] += xv[i].z * w2.z; acc[i][3] += xv[i].z * w2.w;
        acc[i][0] += xv[i].w * w3.x; acc[i][1] += xv[i].w * w3.y;
        acc[i][2] += xv[i].w * w3.z; acc[i][3] += xv[i].w * w3.w;
      }
    }
    __syncthreads();
  }

#pragma unroll
  for (int i = 0; i < TM; ++i) {
    int m = m0 + tr * TM + i;
    if (m < M) {
      ushort4 o;
      o.x = f2bf(acc[i][0]); o.y = f2bf(acc[i][1]);
      o.z = f2bf(acc[i][2]); o.w = f2bf(acc[i][3]);
      *(ushort4*)(out + (size_t)m * BN + tc * 4) = o;
    }
  }
}

// ---------------- node dots (scalar) ----------------
__global__ void node_dots1(const ushort* __restrict__ xp, const float* __restrict__ att,
                           float* __restrict__ ad, float* __restrict__ as_, int N) {
  int idx = blockIdx.x * 256 + threadIdx.x;
  if (idx >= N * 8) return;
  int half = idx & 1, h = (idx >> 1) & 3, n = idx >> 3;
  const ushort* row = xp + (size_t)n * 256 + h * 64;
  const float* wv = att + h * 128 + half * 64;
  float s = 0.f;
  for (int c = 0; c < 64; ++c) s += bf2f(row[c]) * wv[c];
  if (half == 0) ad[n * 4 + h] = s;
  else           as_[n * 4 + h] = s;
}
__global__ void node_dots2(const ushort* __restrict__ hpmu, const ushort* __restrict__ hplv,
                           const float* __restrict__ attmu, const float* __restrict__ attlv,
                           float* __restrict__ a4, int N) {
  int idx = blockIdx.x * 256 + threadIdx.x;
  if (idx >= N * 4) return;
  int w = idx & 3, n = idx >> 2;
  const ushort* hp = (w < 2) ? hpmu : hplv;
  const float* at = (w < 2) ? attmu : attlv;
  const float* wv = at + ((w & 1) ? 128 : 0);
  const ushort* row = hp + (size_t)n * 128;
  float s = 0.f;
  for (int c = 0; c < 128; ++c) s += bf2f(row[c]) * wv[c];
  a4[idx] = s;
}

// ---------------- layer-1 edge kernels (unchanged) ----------------
__global__ void emax1(const int* __restrict__ srcv, const int* __restrict__ dstv,
                      const float* __restrict__ ad, const float* __restrict__ as_,
                      float* __restrict__ amax, int E) {
  int i = blockIdx.x * 256 + threadIdx.x;
  if (i >= E * 4) return;
  int h = i & 3, e = i >> 2;
  float a = ad[dstv[e] * 4 + h] + as_[srcv[e] * 4 + h];
  a = a >= 0.f ? a : NEG_SLOPE * a;
  atomicMaxCAS(&amax[dstv[e] * 4 + h], a);
}
__global__ void epass1(const int* __restrict__ srcv, const int* __restrict__ dstv,
                       const float* __restrict__ ad, const float* __restrict__ as_,
                       const float* __restrict__ amax,
                       float* __restrict__ ex, float* __restrict__ denom, int E) {
  int i = blockIdx.x * 256 + threadIdx.x;
  if (i >= E * 4) return;
  int h = i & 3, e = i >> 2;
  int d = dstv[e];
  float a = ad[d * 4 + h] + as_[srcv[e] * 4 + h];
  a = a >= 0.f ? a : NEG_SLOPE * a;
  float ev = expf(a - amax[d * 4 + h]);
  ex[(size_t)e * 4 + h] = ev;
  atomicAdd(&denom[d * 4 + h], ev);
}

// ---------------- layer-1 CSR aggregation + bias + ELU (atomic-free) -------
__global__ __launch_bounds__(256) void aggregate1_csr(
    const int* __restrict__ row_ptr, const int* __restrict__ csr_e,
    const int* __restrict__ srcv, const float* __restrict__ ew,
    const float* __restrict__ ex, const float* __restrict__ denom,
    const ushort* __restrict__ xp, const float* __restrict__ b1,
    float* __restrict__ hout) {
  int n = blockIdx.x;
  int t = threadIdx.x;          // channel 0..255, head = t>>6
  int h = t >> 6;
  float inv = 1.0f / (denom[n * 4 + h] + SEPS);
  float acc = 0.f;
  int lo = row_ptr[n], hi = row_ptr[n + 1];
  for (int i = lo; i < hi; ++i) {
    int e = csr_e[i];
    int s = srcv[e];
    float coeff = ex[(size_t)e * 4 + h] * inv * ew[e];
    acc += coeff * bf2f(xp[(size_t)s * 256 + t]);
  }
  float val = acc + b1[t];
  hout[(size_t)n * 256 + t] = val > 0.f ? val : expm1f(val);
}

// ---------------- layer-2 edge kernels (unchanged) ----------------
__global__ void emax2(const int* __restrict__ srcv, const int* __restrict__ dstv,
                      const float* __restrict__ a4, float* __restrict__ amax2,
                      int E, int N) {
  int i = blockIdx.x * 256 + threadIdx.x;
  if (i >= E * 2) return;
  int sl = i & 1, e = i >> 1;
  int d = dstv[e];
  float a = a4[d * 4 + sl * 2] + a4[srcv[e] * 4 + sl * 2 + 1];
  a = a >= 0.f ? a : NEG_SLOPE * a;
  atomicMaxCAS(&amax2[(size_t)sl * N + d], a);
}
__global__ void epass2(const int* __restrict__ srcv, const int* __restrict__ dstv,
                       const float* __restrict__ a4, const float* __restrict__ amax2,
                       float* __restrict__ ex2, float* __restrict__ den2, int E, int N) {
  int i = blockIdx.x * 256 + threadIdx.x;
  if (i >= E * 2) return;
  int sl = i & 1, e = i >> 1;
  int d = dstv[e];
  float a = a4[d * 4 + sl * 2] + a4[srcv[e] * 4 + sl * 2 + 1];
  a = a >= 0.f ? a : NEG_SLOPE * a;
  float ev = expf(a - amax2[(size_t)sl * N + d]);
  ex2[(size_t)sl * E + e] = ev;
  atomicAdd(&den2[(size_t)sl * N + d], ev);
}

// ---------------- layer-2 CSR aggregation + bias -> fp32 out ---------------
__global__ __launch_bounds__(256) void aggregate2_csr(
    const int* __restrict__ row_ptr, const int* __restrict__ csr_e,
    const int* __restrict__ srcv, const float* __restrict__ ew,
    const float* __restrict__ ex2, const float* __restrict__ den2,
    const ushort* __restrict__ hpmu, const ushort* __restrict__ hplv,
    const float* __restrict__ bmu, const float* __restrict__ blv,
    float* __restrict__ out, int E, int N) {
  int n = blockIdx.x;
  int t = threadIdx.x;
  int sl = t >> 7;              // 0 = mu, 1 = lv
  int c = t & 127;
  const ushort* hp = sl ? hplv : hpmu;
  float inv = 1.0f / (den2[(size_t)sl * N + n] + SEPS);
  float acc = 0.f;
  int lo = row_ptr[n], hi = row_ptr[n + 1];
  for (int i = lo; i < hi; ++i) {
    int e = csr_e[i];
    int s = srcv[e];
    float coeff = ex2[(size_t)sl * E + e] * inv * ew[e];
    acc += coeff * bf2f(hp[(size_t)s * 128 + c]);
  }
  out[(size_t)sl * N * 128 + (size_t)n * 128 + c] = acc + (sl ? blv[c] : bmu[c]);
}

extern "C" void kernel_launch(void* const* d_in, const int* in_sizes, int n_in,
                              void* d_out, int out_size, void* d_ws, size_t ws_size,
                              hipStream_t stream) {
  int OB = (out_size + 255) / 256;
  bool ok = (n_in == 12);
  int HID = 0, IN = 0, N = 0, LAT = 0, E = 0;
  if (ok) {
    HID = in_sizes[5];
    ok = ok && HID == 256;
    IN = HID ? in_sizes[3] / HID : 0;
    ok = ok && IN == 512 && in_sizes[3] == IN * HID;
    N = IN ? in_sizes[0] / IN : 0;
    ok = ok && N > 0 && in_sizes[0] == N * IN && (N % 4) == 0;
    LAT = in_sizes[8];
    ok = ok && LAT == 128;
    E = in_sizes[2];
    ok = ok && E > 0 && in_sizes[1] == 2 * E;
    ok = ok && in_sizes[4] == 2 * HID && in_sizes[6] == HID * LAT &&
         in_sizes[7] == 2 * LAT && in_sizes[9] == HID * LAT &&
         in_sizes[10] == 2 * LAT && in_sizes[11] == LAT &&
         out_size == 2 * N * LAT;
  }
  if (!ok) { fill_out<<<OB, 256, 0, stream>>>((float*)d_out, out_size, 2.0f); return; }

  char* p = (char*)d_ws;
  auto alloc = [&](size_t bytes) -> char* {
    char* r = p;
    p += (bytes + 255) & ~((size_t)255);
    return r;
  };
  ushort* xp_bf = (ushort*)alloc((size_t)N * HID * 2);   // later: hpmu_bf/hplv_bf
  float*  hreg  = (float*) alloc((size_t)N * HID * 4);
  float*  W1f   = (float*) alloc((size_t)IN * HID * 4);  // natural [K][N] layout
  float*  Wmuf  = (float*) alloc((size_t)HID * LAT * 4);
  float*  Wlvf  = (float*) alloc((size_t)HID * LAT * 4);
  float*  att1f = (float*) alloc((size_t)2 * HID * 4);
  float*  b1f   = (float*) alloc((size_t)HID * 4);
  float*  attmuf= (float*) alloc((size_t)2 * LAT * 4);
  float*  bmuf  = (float*) alloc((size_t)LAT * 4);
  float*  attlvf= (float*) alloc((size_t)2 * LAT * 4);
  float*  blvf  = (float*) alloc((size_t)LAT * 4);
  float*  ewf   = (float*) alloc((size_t)E * 4);
  float*  ad1   = (float*) alloc((size_t)N * 4 * 4);
  float*  as1   = (float*) alloc((size_t)N * 4 * 4);
  float*  a4    = (float*) alloc((size_t)N * 4 * 4);
  float*  ex1   = (float*) alloc((size_t)E * 4 * 4);     // later: ex2 (2E floats)
  float*  amax1 = (float*) alloc((size_t)N * 4 * 4);
  float*  denom1= (float*) alloc((size_t)N * 4 * 4);
  float*  amax2 = (float*) alloc((size_t)2 * N * 4);
  float*  den2  = (float*) alloc((size_t)2 * N * 4);
  int*    srcc  = (int*)   alloc((size_t)E * 4);
  int*    dstc  = (int*)   alloc((size_t)E * 4);
  int*    csr_e = (int*)   alloc((size_t)E * 4);
  int*    row_ptr=(int*)   alloc((size_t)(N + 1) * 4);
  int*    row_cur=(int*)   alloc((size_t)N * 4);
  int*    deg   = (int*)   alloc((size_t)N * 4);
  int*    modes = (int*)   alloc(16 * 4);

  size_t need = (size_t)(p - (char*)d_ws);
  if (need > ws_size) {
    fill_out<<<OB, 256, 0, stream>>>((float*)d_out, out_size, 3.0f);
    return;
  }

  ushort* hpmu_bf = xp_bf;                 // gemm2 writes after aggregate1's last xp read
  ushort* hplv_bf = xp_bf + (size_t)N * LAT;
  float*  ex2     = ex1;                   // epass2 writes after aggregate1's last ex1 read

  // ---- detection + canonicalization ----
  const int fidx[11] = {0, 2, 3, 4, 5, 6, 7, 8, 9, 10, 11};
  for (int i = 0; i < 11; ++i)
    detect_store<<<1, 256, 0, stream>>>((const uint32_t*)d_in[fidx[i]],
                                        in_sizes[fidx[i]], &modes[i]);
  detect_i64<<<1, 256, 0, stream>>>((const uint32_t*)d_in[1], 2 * E, &modes[11]);

  int EB1 = (E + 255) / 256;
  canon_idx<<<EB1, 256, 0, stream>>>(d_in[1], srcc, dstc, E, N, &modes[11]);
  canon_f32<<<EB1, 256, 0, stream>>>(d_in[2], ewf, E, &modes[1]);
  canon_f32<<<(IN * HID + 255) / 256, 256, 0, stream>>>(d_in[3], W1f, IN * HID, &modes[2]);
  canon_f32<<<(HID * LAT + 255) / 256, 256, 0, stream>>>(d_in[6], Wmuf, HID * LAT, &modes[5]);
  canon_f32<<<(HID * LAT + 255) / 256, 256, 0, stream>>>(d_in[9], Wlvf, HID * LAT, &modes[8]);
  canon_f32<<<2, 256, 0, stream>>>(d_in[4], att1f, 2 * HID, &modes[3]);
  canon_f32<<<1, 256, 0, stream>>>(d_in[5], b1f, HID, &modes[4]);
  canon_f32<<<1, 256, 0, stream>>>(d_in[7], attmuf, 2 * LAT, &modes[6]);
  canon_f32<<<1, 256, 0, stream>>>(d_in[8], bmuf, LAT, &modes[7]);
  canon_f32<<<1, 256, 0, stream>>>(d_in[10], attlvf, 2 * LAT, &modes[9]);
  canon_f32<<<1, 256, 0, stream>>>(d_in[11], blvf, LAT, &modes[10]);

  // ---- init fills (small) ----
  fill_f32<<<((N * 4) + 255) / 256, 256, 0, stream>>>(denom1, N * 4, 0.f);
  fill_f32<<<((N * 4) + 255) / 256, 256, 0, stream>>>(amax1, N * 4, -1e30f);
  fill_f32<<<((2 * N) + 255) / 256, 256, 0, stream>>>(amax2, 2 * N, -1e30f);
  fill_f32<<<((2 * N) + 255) / 256, 256, 0, stream>>>(den2, 2 * N, 0.f);
  fill_i32<<<(N + 255) / 256, 256, 0, stream>>>(deg, N, 0);

  int EB4 = (E * 4 + 255) / 256;
  int EB2 = (E * 2 + 255) / 256;

  // ---- CSR build (once; shared by both layers) ----
  count_deg<<<EB1, 256, 0, stream>>>(dstc, deg, E);
  scan_deg<<<1, 1024, 0, stream>>>(deg, row_ptr, row_cur, N);
  scatter_edges<<<EB1, 256, 0, stream>>>(dstc, row_cur, csr_e, E);

  int MB = (N + 31) / 32;

  // ---- layer 1 ----
  gemm_tiled<256><<<MB, 256, 0, stream>>>(d_in[0], W1f, xp_bf, N, IN, &modes[0]);
  node_dots1<<<(N * 8 + 255) / 256, 256, 0, stream>>>(xp_bf, att1f, ad1, as1, N);
  emax1<<<EB4, 256, 0, stream>>>(srcc, dstc, ad1, as1, amax1, E);
  epass1<<<EB4, 256, 0, stream>>>(srcc, dstc, ad1, as1, amax1, ex1, denom1, E);
  aggregate1_csr<<<N, 256, 0, stream>>>(row_ptr, csr_e, srcc, ewf, ex1, denom1,
                                        xp_bf, b1f, hreg);

  // ---- layer 2 ----
  gemm_tiled<128><<<MB, 256, 0, stream>>>(hreg, Wmuf, hpmu_bf, N, HID, nullptr);
  gemm_tiled<128><<<MB, 256, 0, stream>>>(hreg, Wlvf, hplv_bf, N, HID, nullptr);
  node_dots2<<<(N * 4 + 255) / 256, 256, 0, stream>>>(hpmu_bf, hplv_bf, attmuf, attlvf, a4, N);
  emax2<<<EB2, 256, 0, stream>>>(srcc, dstc, a4, amax2, E, N);
  epass2<<<EB2, 256, 0, stream>>>(srcc, dstc, a4, amax2, ex2, den2, E, N);
  aggregate2_csr<<<N, 256, 0, stream>>>(row_ptr, csr_e, srcc, ewf, ex2, den2,
                                        hpmu_bf, hplv_bf, bmuf, blvf,
                                        (float*)d_out, E, N);
}

// Round 2
// 425.026 us; speedup vs baseline: 7.5402x; 1.9156x over previous
//
#include <hip/hip_runtime.h>
#include <stdint.h>

#define NEG_SLOPE 0.2f
#define SEPS 1e-16f

static __device__ __forceinline__ float bf2f(ushort u) {
  union { uint32_t i; float f; } v; v.i = ((uint32_t)u) << 16; return v.f;
}
static __device__ __forceinline__ ushort f2bf(float f) {
  uint32_t b = __float_as_uint(f);
  b += 0x7FFFu + ((b >> 16) & 1u);      // RNE
  return (ushort)(b >> 16);
}
static __device__ __forceinline__ float blo(uint32_t u) { return __uint_as_float(u << 16); }
static __device__ __forceinline__ float bhi(uint32_t u) { return __uint_as_float(u & 0xFFFF0000u); }
static __device__ __forceinline__ float ldf(const void* p, size_t i, int mode) {
  return mode ? ((const float*)p)[i] : bf2f(((const ushort*)p)[i]);
}

// ---------------- fills ----------------
__global__ void fill_out(float* __restrict__ out, int n, float v) {
  int i = blockIdx.x * 256 + threadIdx.x;
  if (i < n) out[i] = v;
}
__global__ void fill_i32(int* __restrict__ p, int n, int v) {
  int i = blockIdx.x * 256 + threadIdx.x;
  if (i < n) p[i] = v;
}

// ---------------- fused storage detectors (one launch, 12 blocks) ---------
struct DetPtrs {
  const uint32_t* p[11];
  int n[11];
  const uint32_t* idx;
  int idxn;
};
__global__ void detect_all(DetPtrs dp, int* __restrict__ modes) {
  int b = blockIdx.x;
  __shared__ int sL, sH;
  if (threadIdx.x == 0) { sL = 0; sH = 0; }
  __syncthreads();
  if (b < 11) {
    const uint32_t* w = dp.p[b];
    int elems = dp.n[b];
    int nprobe = min(2048, elems / 2);
    int cL = 0, cH = 0;
    for (int i = threadIdx.x; i < nprobe; i += 256) {
      uint32_t v = w[i];
      uint32_t eL = (v >> 7) & 0xFFu;
      uint32_t eH = (v >> 23) & 0xFFu;
      if (eL >= 90u && eL <= 128u) cL++;
      if (eH >= 90u && eH <= 128u) cH++;
    }
    atomicAdd(&sL, cL); atomicAdd(&sH, cH);
    __syncthreads();
    if (threadIdx.x == 0) {
      int m;
      if (sL * 4 >= nprobe * 3) m = 0;
      else if (sH * 4 >= nprobe) m = 1;
      else m = 0;
      modes[b] = m;
    }
  } else {
    const uint32_t* w = dp.idx;
    int nprobe = min(4096, dp.idxn);
    int c = 0;
    for (int i = threadIdx.x; i < nprobe; i += 256)
      if ((i & 1) && w[i] == 0u) c++;
    atomicAdd(&sL, c);
    __syncthreads();
    if (threadIdx.x == 0) modes[11] = (sL * 4 >= (nprobe / 2) * 3) ? 1 : 0;
  }
}

// ---------------- canonicalizers ----------------
__global__ void canon_idx(const void* __restrict__ ei, int* __restrict__ srcc,
                          int* __restrict__ dstc, int E, int N,
                          const int* __restrict__ m64) {
  int i = blockIdx.x * 256 + threadIdx.x;
  if (i >= E) return;
  int s, d;
  if (*m64) {
    s = (int)((const long long*)ei)[i];
    d = (int)((const long long*)ei)[E + i];
  } else {
    s = ((const int*)ei)[i];
    d = ((const int*)ei)[E + i];
  }
  srcc[i] = min(max(s, 0), N - 1);
  dstc[i] = min(max(d, 0), N - 1);
}
__global__ void canon_f32(const void* __restrict__ in, float* __restrict__ out,
                          int n, const int* __restrict__ mode) {
  int i = blockIdx.x * 256 + threadIdx.x;
  if (i >= n) return;
  float v = ldf(in, i, *mode);
  if (!isfinite(v)) v = 0.f;
  out[i] = v;
}
struct W3Args { const void* src[3]; float* dst[3]; int n[3]; int mi[3]; };
__global__ void canon_w3(W3Args a, const int* __restrict__ modes) {
  int i = blockIdx.x * 256 + threadIdx.x;
  int b, off;
  int n01 = a.n[0] + a.n[1];
  if (i < a.n[0]) { b = 0; off = i; }
  else if (i < n01) { b = 1; off = i - a.n[0]; }
  else if (i < n01 + a.n[2]) { b = 2; off = i - n01; }
  else return;
  float v = ldf(a.src[b], off, modes[a.mi[b]]);
  if (!isfinite(v)) v = 0.f;
  a.dst[b][off] = v;
}
struct SmallCan { const void* src[6]; float* dst[6]; int n[6]; int mi[6]; };
__global__ void canon_small(SmallCan a, const int* __restrict__ modes) {
  int b = blockIdx.x;
  int m = modes[a.mi[b]];
  const void* s = a.src[b];
  float* d = a.dst[b];
  for (int i = threadIdx.x; i < a.n[b]; i += 256) {
    float v = ldf(s, i, m);
    if (!isfinite(v)) v = 0.f;
    d[i] = v;
  }
}

// ---------------- CSR build (src/weight stored directly) ----------------
__global__ void count_deg(const int* __restrict__ dstv, int* __restrict__ deg, int E) {
  int e = blockIdx.x * 256 + threadIdx.x;
  if (e < E) atomicAdd(&deg[dstv[e]], 1);
}
__global__ __launch_bounds__(1024) void scan_deg(const int* __restrict__ deg,
                                                 int* __restrict__ row_ptr,
                                                 int* __restrict__ row_cur, int N) {
  __shared__ int part[1024];
  int t = threadIdx.x;
  int chunk = (N + 1023) / 1024;
  int lo = t * chunk, hi = min(lo + chunk, N);
  int s = 0;
  for (int i = lo; i < hi; ++i) s += deg[i];
  part[t] = s;
  __syncthreads();
  for (int off = 1; off < 1024; off <<= 1) {
    int v = (t >= off) ? part[t - off] : 0;
    __syncthreads();
    part[t] += v;
    __syncthreads();
  }
  int base = (t == 0) ? 0 : part[t - 1];
  for (int i = lo; i < hi; ++i) {
    row_ptr[i] = base; row_cur[i] = base;
    base += deg[i];
  }
  if (t == 1023) row_ptr[N] = part[1023];
}
__global__ void scatter_edges(const int* __restrict__ dstv, const int* __restrict__ srcv,
                              const float* __restrict__ ew, int* __restrict__ row_cur,
                              int* __restrict__ csr_src, float* __restrict__ csr_w, int E) {
  int e = blockIdx.x * 256 + threadIdx.x;
  if (e < E) {
    int p = atomicAdd(&row_cur[dstv[e]], 1);
    csr_src[p] = srcv[e];
    csr_w[p] = ew[e];
  }
}

// ---------------- tiled GEMM: out_bf16[M,BN] = A[M,K] @ W[K,BN] -----------
template <int BN>
__global__ __launch_bounds__(256) void gemm_tiled(
    const void* __restrict__ A, const float* __restrict__ W,
    ushort* __restrict__ out, int M, int K,
    const int* __restrict__ modeA) {
  constexpr int BM = 32;
  constexpr int BK = 32;
  constexpr int CG = BN / 4;        // column groups (64 or 32)
  constexpr int RG = 256 / CG;      // row groups (4 or 8)
  constexpr int TM = BM / RG;       // rows per thread (8 or 4)
  __shared__ float Xs[BM][BK + 4];
  __shared__ float Ws[BK][BN];

  int t = threadIdx.x;
  int m0 = blockIdx.x * BM;
  int tc = t % CG;
  int tr = t / CG;

  float acc[TM][4];
#pragma unroll
  for (int i = 0; i < TM; ++i) { acc[i][0] = acc[i][1] = acc[i][2] = acc[i][3] = 0.f; }

  int mode = modeA ? *modeA : 1;

  int sxm = t >> 3;
  int sxk = (t & 7) * 4;
  int srow = min(m0 + sxm, M - 1);

  for (int k0 = 0; k0 < K; k0 += BK) {
    if (mode) {
      const float4 v = *(const float4*)((const float*)A + (size_t)srow * K + k0 + sxk);
      Xs[sxm][sxk + 0] = v.x; Xs[sxm][sxk + 1] = v.y;
      Xs[sxm][sxk + 2] = v.z; Xs[sxm][sxk + 3] = v.w;
    } else {
      const ushort4 v = *(const ushort4*)((const ushort*)A + (size_t)srow * K + k0 + sxk);
      Xs[sxm][sxk + 0] = bf2f(v.x); Xs[sxm][sxk + 1] = bf2f(v.y);
      Xs[sxm][sxk + 2] = bf2f(v.z); Xs[sxm][sxk + 3] = bf2f(v.w);
    }
    constexpr int PER = (BK * BN) / 1024;
#pragma unroll
    for (int i = 0; i < PER; ++i) {
      int f = t + i * 256;
      int kk = (f * 4) / BN;
      int nn = (f * 4) % BN;
      *(float4*)&Ws[kk][nn] = *(const float4*)&W[(size_t)(k0 + kk) * BN + nn];
    }
    __syncthreads();

#pragma unroll
    for (int k4 = 0; k4 < BK; k4 += 4) {
      float4 xv[TM];
#pragma unroll
      for (int i = 0; i < TM; ++i)
        xv[i] = *(const float4*)&Xs[tr * TM + i][k4];
      float4 w0 = *(const float4*)&Ws[k4 + 0][tc * 4];
      float4 w1 = *(const float4*)&Ws[k4 + 1][tc * 4];
      float4 w2 = *(const float4*)&Ws[k4 + 2][tc * 4];
      float4 w3 = *(const float4*)&Ws[k4 + 3][tc * 4];
#pragma unroll
      for (int i = 0; i < TM; ++i) {
        acc[i][0] += xv[i].x * w0.x; acc[i][1] += xv[i].x * w0.y;
        acc[i][2] += xv[i].x * w0.z; acc[i][3] += xv[i].x * w0.w;
        acc[i][0] += xv[i].y * w1.x; acc[i][1] += xv[i].y * w1.y;
        acc[i][2] += xv[i].y * w1.z; acc[i][3] += xv[i].y * w1.w;
        acc[i][0] += xv[i].z * w2.x; acc[i][1] += xv[i].z * w2.y;
        acc[i][2] += xv[i].z * w2.z; acc[i][3] += xv[i].z * w2.w;
        acc[i][0] += xv[i].w * w3.x; acc[i][1] += xv[i].w * w3.y;
        acc[i][2] += xv[i].w * w3.z; acc[i][3] += xv[i].w * w3.w;
      }
    }
    __syncthreads();
  }

#pragma unroll
  for (int i = 0; i < TM; ++i) {
    int m = m0 + tr * TM + i;
    if (m < M) {
      ushort4 o;
      o.x = f2bf(acc[i][0]); o.y = f2bf(acc[i][1]);
      o.z = f2bf(acc[i][2]); o.w = f2bf(acc[i][3]);
      *(ushort4*)(out + (size_t)m * BN + tc * 4) = o;
    }
  }
}

// ---------------- node dots (vectorized uint4 loads) ----------------
__global__ void node_dots1(const ushort* __restrict__ xp, const float* __restrict__ att,
                           float* __restrict__ ad, float* __restrict__ as_, int N) {
  int idx = blockIdx.x * 256 + threadIdx.x;
  if (idx >= N * 8) return;
  int half = idx & 1, h = (idx >> 1) & 3, n = idx >> 3;
  const ushort* row = xp + (size_t)n * 256 + h * 64;
  const float* wv = att + h * 128 + half * 64;
  float s = 0.f;
#pragma unroll
  for (int c = 0; c < 64; c += 8) {
    uint4 v = *(const uint4*)(row + c);
    s += blo(v.x) * wv[c + 0] + bhi(v.x) * wv[c + 1]
       + blo(v.y) * wv[c + 2] + bhi(v.y) * wv[c + 3]
       + blo(v.z) * wv[c + 4] + bhi(v.z) * wv[c + 5]
       + blo(v.w) * wv[c + 6] + bhi(v.w) * wv[c + 7];
  }
  if (half == 0) ad[n * 4 + h] = s;
  else           as_[n * 4 + h] = s;
}
__global__ void node_dots2(const ushort* __restrict__ hpmu, const ushort* __restrict__ hplv,
                           const float* __restrict__ attmu, const float* __restrict__ attlv,
                           float* __restrict__ a4, int N) {
  int idx = blockIdx.x * 256 + threadIdx.x;
  if (idx >= N * 4) return;
  int w = idx & 3, n = idx >> 2;
  const ushort* hp = (w < 2) ? hpmu : hplv;
  const float* at = (w < 2) ? attmu : attlv;
  const float* wv = at + ((w & 1) ? 128 : 0);
  const ushort* row = hp + (size_t)n * 128;
  float s = 0.f;
#pragma unroll
  for (int c = 0; c < 128; c += 8) {
    uint4 v = *(const uint4*)(row + c);
    s += blo(v.x) * wv[c + 0] + bhi(v.x) * wv[c + 1]
       + blo(v.y) * wv[c + 2] + bhi(v.y) * wv[c + 3]
       + blo(v.z) * wv[c + 4] + bhi(v.z) * wv[c + 5]
       + blo(v.w) * wv[c + 6] + bhi(v.w) * wv[c + 7];
  }
  a4[idx] = s;
}

// -------- layer-1 fused softmax + aggregation + bias + ELU (CSR) ----------
// block = node; 256 threads = 8 edge-groups x 32 lanes; lane covers 8 channels.
__global__ __launch_bounds__(256) void fused_agg1(
    const int* __restrict__ row_ptr, const int* __restrict__ csr_src,
    const float* __restrict__ csr_w,
    const float* __restrict__ ad, const float* __restrict__ as_,
    const ushort* __restrict__ xp, const float* __restrict__ b1,
    float* __restrict__ hout) {
  int n = blockIdx.x;
  int t = threadIdx.x;
  int g = t >> 5;                 // edge group 0..7
  int l = t & 31;                 // lane; channels 8l..8l+7
  int h = l >> 3;                 // head of these channels
  __shared__ float red_m[8][32];
  __shared__ float red_d[8][32];
  __shared__ float red_acc[8][256];

  int lo = row_ptr[n], hi = row_ptr[n + 1];
  float adv = ad[n * 4 + h];

  // phase A: per-node max of leaky(alpha)
  float m = -1e30f;
  for (int i = lo + g; i < hi; i += 8) {
    int s = csr_src[i];
    float a = adv + as_[s * 4 + h];
    a = a >= 0.f ? a : NEG_SLOPE * a;
    m = fmaxf(m, a);
  }
  red_m[g][l] = m;
  __syncthreads();
  m = red_m[0][l];
#pragma unroll
  for (int gg = 1; gg < 8; ++gg) m = fmaxf(m, red_m[gg][l]);

  // phase B: exp, denom, weighted gather-accumulate (1/denom factors out)
  float acc[8];
#pragma unroll
  for (int j = 0; j < 8; ++j) acc[j] = 0.f;
  float dsum = 0.f;
  for (int i = lo + g; i < hi; i += 8) {
    int s = csr_src[i];
    float a = adv + as_[s * 4 + h];
    a = a >= 0.f ? a : NEG_SLOPE * a;
    float ev = expf(a - m);
    dsum += ev;
    float cw = ev * csr_w[i];
    uint4 v = *(const uint4*)(xp + (size_t)s * 256 + l * 8);
    acc[0] += cw * blo(v.x); acc[1] += cw * bhi(v.x);
    acc[2] += cw * blo(v.y); acc[3] += cw * bhi(v.y);
    acc[4] += cw * blo(v.z); acc[5] += cw * bhi(v.z);
    acc[6] += cw * blo(v.w); acc[7] += cw * bhi(v.w);
  }
  red_d[g][l] = dsum;
#pragma unroll
  for (int j = 0; j < 8; ++j) red_acc[g][l * 8 + j] = acc[j];
  __syncthreads();

  // final: thread t owns channel t
  float v = 0.f;
#pragma unroll
  for (int gg = 0; gg < 8; ++gg) v += red_acc[gg][t];
  int h2 = t >> 6;
  float den = 0.f;
#pragma unroll
  for (int gg = 0; gg < 8; ++gg) den += red_d[gg][h2 << 3];
  float inv = 1.0f / (den + SEPS);
  float val = v * inv + b1[t];
  hout[(size_t)n * 256 + t] = val > 0.f ? val : expm1f(val);
}

// -------- layer-2 fused softmax + aggregation + bias (mu & lv) ------------
// block = node; 256 threads: sl = t>>7 (mu/lv); per sl: 8 groups x 16 lanes.
__global__ __launch_bounds__(256) void fused_agg2(
    const int* __restrict__ row_ptr, const int* __restrict__ csr_src,
    const float* __restrict__ csr_w, const float* __restrict__ a4,
    const ushort* __restrict__ hpmu, const ushort* __restrict__ hplv,
    const float* __restrict__ bmu, const float* __restrict__ blv,
    float* __restrict__ out, int N) {
  int n = blockIdx.x;
  int t = threadIdx.x;
  int sl = t >> 7;                // 0 = mu, 1 = lv
  int u = t & 127;
  int g = u >> 4;                 // edge group 0..7
  int l = u & 15;                 // lane; channels 8l..8l+7
  const ushort* hp = sl ? hplv : hpmu;
  __shared__ float red_m2[2][8];
  __shared__ float red_d2[2][8];
  __shared__ float red_acc2[2][8][128];

  int lo = row_ptr[n], hi = row_ptr[n + 1];
  float adv = a4[n * 4 + sl * 2];

  float m = -1e30f;
  for (int i = lo + g; i < hi; i += 8) {
    int s = csr_src[i];
    float a = adv + a4[s * 4 + sl * 2 + 1];
    a = a >= 0.f ? a : NEG_SLOPE * a;
    m = fmaxf(m, a);
  }
  if (l == 0) red_m2[sl][g] = m;
  __syncthreads();
  m = red_m2[sl][0];
#pragma unroll
  for (int gg = 1; gg < 8; ++gg) m = fmaxf(m, red_m2[sl][gg]);

  float acc[8];
#pragma unroll
  for (int j = 0; j < 8; ++j) acc[j] = 0.f;
  float dsum = 0.f;
  for (int i = lo + g; i < hi; i += 8) {
    int s = csr_src[i];
    float a = adv + a4[s * 4 + sl * 2 + 1];
    a = a >= 0.f ? a : NEG_SLOPE * a;
    float ev = expf(a - m);
    dsum += ev;
    float cw = ev * csr_w[i];
    uint4 v = *(const uint4*)(hp + (size_t)s * 128 + l * 8);
    acc[0] += cw * blo(v.x); acc[1] += cw * bhi(v.x);
    acc[2] += cw * blo(v.y); acc[3] += cw * bhi(v.y);
    acc[4] += cw * blo(v.z); acc[5] += cw * bhi(v.z);
    acc[6] += cw * blo(v.w); acc[7] += cw * bhi(v.w);
  }
  if (l == 0) red_d2[sl][g] = dsum;
#pragma unroll
  for (int j = 0; j < 8; ++j) red_acc2[sl][g][l * 8 + j] = acc[j];
  __syncthreads();

  float v = 0.f;
#pragma unroll
  for (int gg = 0; gg < 8; ++gg) v += red_acc2[sl][gg][u];
  float den = 0.f;
#pragma unroll
  for (int gg = 0; gg < 8; ++gg) den += red_d2[sl][gg];
  float inv = 1.0f / (den + SEPS);
  out[(size_t)sl * N * 128 + (size_t)n * 128 + u] = v * inv + (sl ? blv[u] : bmu[u]);
}

extern "C" void kernel_launch(void* const* d_in, const int* in_sizes, int n_in,
                              void* d_out, int out_size, void* d_ws, size_t ws_size,
                              hipStream_t stream) {
  int OB = (out_size + 255) / 256;
  bool ok = (n_in == 12);
  int HID = 0, IN = 0, N = 0, LAT = 0, E = 0;
  if (ok) {
    HID = in_sizes[5];
    ok = ok && HID == 256;
    IN = HID ? in_sizes[3] / HID : 0;
    ok = ok && IN == 512 && in_sizes[3] == IN * HID;
    N = IN ? in_sizes[0] / IN : 0;
    ok = ok && N > 0 && in_sizes[0] == N * IN && (N % 4) == 0;
    LAT = in_sizes[8];
    ok = ok && LAT == 128;
    E = in_sizes[2];
    ok = ok && E > 0 && in_sizes[1] == 2 * E;
    ok = ok && in_sizes[4] == 2 * HID && in_sizes[6] == HID * LAT &&
         in_sizes[7] == 2 * LAT && in_sizes[9] == HID * LAT &&
         in_sizes[10] == 2 * LAT && in_sizes[11] == LAT &&
         out_size == 2 * N * LAT;
  }
  if (!ok) { fill_out<<<OB, 256, 0, stream>>>((float*)d_out, out_size, 2.0f); return; }

  char* p = (char*)d_ws;
  auto alloc = [&](size_t bytes) -> char* {
    char* r = p;
    p += (bytes + 255) & ~((size_t)255);
    return r;
  };
  ushort* xp_bf = (ushort*)alloc((size_t)N * HID * 2);   // later: hpmu_bf/hplv_bf
  float*  hreg  = (float*) alloc((size_t)N * HID * 4);
  float*  W1f   = (float*) alloc((size_t)IN * HID * 4);
  float*  Wmuf  = (float*) alloc((size_t)HID * LAT * 4);
  float*  Wlvf  = (float*) alloc((size_t)HID * LAT * 4);
  float*  att1f = (float*) alloc((size_t)2 * HID * 4);
  float*  b1f   = (float*) alloc((size_t)HID * 4);
  float*  attmuf= (float*) alloc((size_t)2 * LAT * 4);
  float*  bmuf  = (float*) alloc((size_t)LAT * 4);
  float*  attlvf= (float*) alloc((size_t)2 * LAT * 4);
  float*  blvf  = (float*) alloc((size_t)LAT * 4);
  float*  ewf   = (float*) alloc((size_t)E * 4);
  float*  ad1   = (float*) alloc((size_t)N * 4 * 4);
  float*  as1   = (float*) alloc((size_t)N * 4 * 4);
  float*  a4    = (float*) alloc((size_t)N * 4 * 4);
  int*    srcc  = (int*)   alloc((size_t)E * 4);
  int*    dstc  = (int*)   alloc((size_t)E * 4);
  int*    csr_src=(int*)   alloc((size_t)E * 4);
  float*  csr_w = (float*) alloc((size_t)E * 4);
  int*    row_ptr=(int*)   alloc((size_t)(N + 1) * 4);
  int*    row_cur=(int*)   alloc((size_t)N * 4);
  int*    deg   = (int*)   alloc((size_t)N * 4);
  int*    modes = (int*)   alloc(16 * 4);

  size_t need = (size_t)(p - (char*)d_ws);
  if (need > ws_size) {
    fill_out<<<OB, 256, 0, stream>>>((float*)d_out, out_size, 3.0f);
    return;
  }

  ushort* hpmu_bf = xp_bf;                 // gemm2 writes after fused_agg1's last xp read
  ushort* hplv_bf = xp_bf + (size_t)N * LAT;

  // ---- detection (single launch) ----
  const int fidx[11] = {0, 2, 3, 4, 5, 6, 7, 8, 9, 10, 11};
  DetPtrs dp;
  for (int i = 0; i < 11; ++i) {
    dp.p[i] = (const uint32_t*)d_in[fidx[i]];
    dp.n[i] = in_sizes[fidx[i]];
  }
  dp.idx = (const uint32_t*)d_in[1];
  dp.idxn = 2 * E;
  detect_all<<<12, 256, 0, stream>>>(dp, modes);

  // ---- canonicalization ----
  int EB1 = (E + 255) / 256;
  canon_idx<<<EB1, 256, 0, stream>>>(d_in[1], srcc, dstc, E, N, &modes[11]);
  canon_f32<<<EB1, 256, 0, stream>>>(d_in[2], ewf, E, &modes[1]);
  W3Args w3;
  w3.src[0] = d_in[3]; w3.dst[0] = W1f;  w3.n[0] = IN * HID;  w3.mi[0] = 2;
  w3.src[1] = d_in[6]; w3.dst[1] = Wmuf; w3.n[1] = HID * LAT; w3.mi[1] = 5;
  w3.src[2] = d_in[9]; w3.dst[2] = Wlvf; w3.n[2] = HID * LAT; w3.mi[2] = 8;
  int wtot = IN * HID + 2 * HID * LAT;
  canon_w3<<<(wtot + 255) / 256, 256, 0, stream>>>(w3, modes);
  SmallCan sc;
  sc.src[0] = d_in[4];  sc.dst[0] = att1f;  sc.n[0] = 2 * HID; sc.mi[0] = 3;
  sc.src[1] = d_in[5];  sc.dst[1] = b1f;    sc.n[1] = HID;     sc.mi[1] = 4;
  sc.src[2] = d_in[7];  sc.dst[2] = attmuf; sc.n[2] = 2 * LAT; sc.mi[2] = 6;
  sc.src[3] = d_in[8];  sc.dst[3] = bmuf;   sc.n[3] = LAT;     sc.mi[3] = 7;
  sc.src[4] = d_in[10]; sc.dst[4] = attlvf; sc.n[4] = 2 * LAT; sc.mi[4] = 9;
  sc.src[5] = d_in[11]; sc.dst[5] = blvf;   sc.n[5] = LAT;     sc.mi[5] = 10;
  canon_small<<<6, 256, 0, stream>>>(sc, modes);

  fill_i32<<<(N + 255) / 256, 256, 0, stream>>>(deg, N, 0);

  // ---- CSR build (src + weight stored at scatter; shared by both layers) ----
  count_deg<<<EB1, 256, 0, stream>>>(dstc, deg, E);
  scan_deg<<<1, 1024, 0, stream>>>(deg, row_ptr, row_cur, N);
  scatter_edges<<<EB1, 256, 0, stream>>>(dstc, srcc, ewf, row_cur, csr_src, csr_w, E);

  int MB = (N + 31) / 32;

  // ---- layer 1 ----
  gemm_tiled<256><<<MB, 256, 0, stream>>>(d_in[0], W1f, xp_bf, N, IN, &modes[0]);
  node_dots1<<<(N * 8 + 255) / 256, 256, 0, stream>>>(xp_bf, att1f, ad1, as1, N);
  fused_agg1<<<N, 256, 0, stream>>>(row_ptr, csr_src, csr_w, ad1, as1,
                                    xp_bf, b1f, hreg);

  // ---- layer 2 ----
  gemm_tiled<128><<<MB, 256, 0, stream>>>(hreg, Wmuf, hpmu_bf, N, HID, nullptr);
  gemm_tiled<128><<<MB, 256, 0, stream>>>(hreg, Wlvf, hplv_bf, N, HID, nullptr);
  node_dots2<<<(N * 4 + 255) / 256, 256, 0, stream>>>(hpmu_bf, hplv_bf, attmuf, attlvf, a4, N);
  fused_agg2<<<N, 256, 0, stream>>>(row_ptr, csr_src, csr_w, a4,
                                    hpmu_bf, hplv_bf, bmuf, blvf,
                                    (float*)d_out, N);
}

// Round 3
// 331.259 us; speedup vs baseline: 9.6746x; 1.2831x over previous
//
#include <hip/hip_runtime.h>
#include <stdint.h>

#define NEG_SLOPE 0.2f
#define SEPS 1e-16f

typedef short bf16x8 __attribute__((ext_vector_type(8)));
typedef float f32x4 __attribute__((ext_vector_type(4)));

static __device__ __forceinline__ float bf2f(ushort u) {
  union { uint32_t i; float f; } v; v.i = ((uint32_t)u) << 16; return v.f;
}
static __device__ __forceinline__ ushort f2bf(float f) {
  uint32_t b = __float_as_uint(f);
  b += 0x7FFFu + ((b >> 16) & 1u);      // RNE
  return (ushort)(b >> 16);
}
static __device__ __forceinline__ float blo(uint32_t u) { return __uint_as_float(u << 16); }
static __device__ __forceinline__ float bhi(uint32_t u) { return __uint_as_float(u & 0xFFFF0000u); }
static __device__ __forceinline__ float ldf(const void* p, size_t i, int mode) {
  return mode ? ((const float*)p)[i] : bf2f(((const ushort*)p)[i]);
}

// ---------------- fills ----------------
__global__ void fill_out(float* __restrict__ out, int n, float v) {
  int i = blockIdx.x * 256 + threadIdx.x;
  if (i < n) out[i] = v;
}
__global__ void fill_i32(int* __restrict__ p, int n, int v) {
  int i = blockIdx.x * 256 + threadIdx.x;
  if (i < n) p[i] = v;
}

// ---------------- fused storage detectors (one launch, 12 blocks) ---------
struct DetPtrs {
  const uint32_t* p[11];
  int n[11];
  const uint32_t* idx;
  int idxn;
};
__global__ void detect_all(DetPtrs dp, int* __restrict__ modes) {
  int b = blockIdx.x;
  __shared__ int sL, sH;
  if (threadIdx.x == 0) { sL = 0; sH = 0; }
  __syncthreads();
  if (b < 11) {
    const uint32_t* w = dp.p[b];
    int elems = dp.n[b];
    int nprobe = min(2048, elems / 2);
    int cL = 0, cH = 0;
    for (int i = threadIdx.x; i < nprobe; i += 256) {
      uint32_t v = w[i];
      uint32_t eL = (v >> 7) & 0xFFu;
      uint32_t eH = (v >> 23) & 0xFFu;
      if (eL >= 90u && eL <= 128u) cL++;
      if (eH >= 90u && eH <= 128u) cH++;
    }
    atomicAdd(&sL, cL); atomicAdd(&sH, cH);
    __syncthreads();
    if (threadIdx.x == 0) {
      int m;
      if (sL * 4 >= nprobe * 3) m = 0;
      else if (sH * 4 >= nprobe) m = 1;
      else m = 0;
      modes[b] = m;
    }
  } else {
    const uint32_t* w = dp.idx;
    int nprobe = min(4096, dp.idxn);
    int c = 0;
    for (int i = threadIdx.x; i < nprobe; i += 256)
      if ((i & 1) && w[i] == 0u) c++;
    atomicAdd(&sL, c);
    __syncthreads();
    if (threadIdx.x == 0) modes[11] = (sL * 4 >= (nprobe / 2) * 3) ? 1 : 0;
  }
}

// ---------------- canonicalizers ----------------
__global__ void canon_idx(const void* __restrict__ ei, int* __restrict__ srcc,
                          int* __restrict__ dstc, int E, int N,
                          const int* __restrict__ m64) {
  int i = blockIdx.x * 256 + threadIdx.x;
  if (i >= E) return;
  int s, d;
  if (*m64) {
    s = (int)((const long long*)ei)[i];
    d = (int)((const long long*)ei)[E + i];
  } else {
    s = ((const int*)ei)[i];
    d = ((const int*)ei)[E + i];
  }
  srcc[i] = min(max(s, 0), N - 1);
  dstc[i] = min(max(d, 0), N - 1);
}
__global__ void canon_f32(const void* __restrict__ in, float* __restrict__ out,
                          int n, const int* __restrict__ mode) {
  int i = blockIdx.x * 256 + threadIdx.x;
  if (i >= n) return;
  float v = ldf(in, i, *mode);
  if (!isfinite(v)) v = 0.f;
  out[i] = v;
}
// transposed bf16 weight canon: WT1b[256][512] from W1[512][256];
// WallT[256][256]: rows 0..127 from Wmu[256][128], rows 128..255 from Wlv.
struct WTArgs {
  const void* w1; const void* wmu; const void* wlv;
  ushort* wt1; ushort* wall;
};
__global__ void canon_wt(WTArgs a, const int* __restrict__ modes) {
  int i = blockIdx.x * 256 + threadIdx.x;
  const int NW1 = 256 * 512;
  if (i < NW1) {
    int n = i >> 9, k = i & 511;
    float v = ldf(a.w1, (size_t)k * 256 + n, modes[2]);
    if (!isfinite(v)) v = 0.f;
    a.wt1[i] = f2bf(v);
  } else {
    int j = i - NW1;
    if (j >= 256 * 256) return;
    int n = j >> 8, k = j & 255;
    float v;
    if (n < 128) v = ldf(a.wmu, (size_t)k * 128 + n, modes[5]);
    else         v = ldf(a.wlv, (size_t)k * 128 + (n - 128), modes[8]);
    if (!isfinite(v)) v = 0.f;
    a.wall[j] = f2bf(v);
  }
}
struct SmallCan { const void* src[6]; float* dst[6]; int n[6]; int mi[6]; };
__global__ void canon_small(SmallCan a, const int* __restrict__ modes) {
  int b = blockIdx.x;
  int m = modes[a.mi[b]];
  const void* s = a.src[b];
  float* d = a.dst[b];
  for (int i = threadIdx.x; i < a.n[b]; i += 256) {
    float v = ldf(s, i, m);
    if (!isfinite(v)) v = 0.f;
    d[i] = v;
  }
}

// ---------------- CSR build ----------------
__global__ void count_deg(const int* __restrict__ dstv, int* __restrict__ deg, int E) {
  int e = blockIdx.x * 256 + threadIdx.x;
  if (e < E) atomicAdd(&deg[dstv[e]], 1);
}
__global__ __launch_bounds__(1024) void scan_deg(const int* __restrict__ deg,
                                                 int* __restrict__ row_ptr,
                                                 int* __restrict__ row_cur, int N) {
  __shared__ int part[1024];
  int t = threadIdx.x;
  int chunk = (N + 1023) / 1024;
  int lo = t * chunk, hi = min(lo + chunk, N);
  int s = 0;
  for (int i = lo; i < hi; ++i) s += deg[i];
  part[t] = s;
  __syncthreads();
  for (int off = 1; off < 1024; off <<= 1) {
    int v = (t >= off) ? part[t - off] : 0;
    __syncthreads();
    part[t] += v;
    __syncthreads();
  }
  int base = (t == 0) ? 0 : part[t - 1];
  for (int i = lo; i < hi; ++i) {
    row_ptr[i] = base; row_cur[i] = base;
    base += deg[i];
  }
  if (t == 1023) row_ptr[N] = part[1023];
}
__global__ void scatter_edges(const int* __restrict__ dstv, const int* __restrict__ srcv,
                              const float* __restrict__ ew, int* __restrict__ row_cur,
                              int* __restrict__ csr_src, float* __restrict__ csr_w, int E) {
  int e = blockIdx.x * 256 + threadIdx.x;
  if (e < E) {
    int p = atomicAdd(&row_cur[dstv[e]], 1);
    csr_src[p] = srcv[e];
    csr_w[p] = ew[e];
  }
}

// ---------------- MFMA GEMM: out_bf16[M][nTot] = A[M][K] @ WT^T ----------
// WT is bf16 [nTot][K] (pre-transposed). Block tile 64x128, 4 waves (2x2),
// per wave 32x64 = 2x4 frags of 16x16, BK=32 (one MFMA K per step).
template <int KTOT>
__global__ __launch_bounds__(256) void gemm_mfma(
    const void* __restrict__ A, const ushort* __restrict__ WT,
    ushort* __restrict__ out, int M, int nTot,
    const int* __restrict__ modeA) {
  __shared__ ushort As[64][40];    // 80B row pitch: 2-way bank alias (free)
  __shared__ ushort Bs[128][40];

  int t = threadIdx.x;
  int m0 = blockIdx.x * 64;
  int n0 = blockIdx.y * 128;
  int wid = t >> 6, l = t & 63;
  int wr = wid >> 1, wc = wid & 1;
  int mode = modeA ? *modeA : 1;

  int arow = t >> 2;               // 0..63
  int akoff = (t & 3) * 8;         // k offset in tile
  int srow = min(m0 + arow, M - 1);
  int brow = t >> 1;               // 0..127
  int bkoff = (t & 1) * 16;

  f32x4 acc[2][4];
#pragma unroll
  for (int i = 0; i < 2; ++i)
#pragma unroll
    for (int j = 0; j < 4; ++j) acc[i][j] = (f32x4){0.f, 0.f, 0.f, 0.f};

  int cl = l & 15;
  int ksl = (l >> 4) * 8;

  for (int k0 = 0; k0 < KTOT; k0 += 32) {
    // ---- stage A (64x32 bf16) ----
    if (mode) {
      const float* Af = (const float*)A + (size_t)srow * KTOT + k0 + akoff;
      float4 v0 = *(const float4*)Af;
      float4 v1 = *(const float4*)(Af + 4);
      uint4 pk;
      pk.x = (uint32_t)f2bf(v0.x) | ((uint32_t)f2bf(v0.y) << 16);
      pk.y = (uint32_t)f2bf(v0.z) | ((uint32_t)f2bf(v0.w) << 16);
      pk.z = (uint32_t)f2bf(v1.x) | ((uint32_t)f2bf(v1.y) << 16);
      pk.w = (uint32_t)f2bf(v1.z) | ((uint32_t)f2bf(v1.w) << 16);
      *(uint4*)&As[arow][akoff] = pk;
    } else {
      *(uint4*)&As[arow][akoff] =
          *(const uint4*)((const ushort*)A + (size_t)srow * KTOT + k0 + akoff);
    }
    // ---- stage B^T (128 cols x 32 k) ----
    {
      const ushort* wp = WT + (size_t)(n0 + brow) * KTOT + k0 + bkoff;
      *(uint4*)&Bs[brow][bkoff] = *(const uint4*)wp;
      *(uint4*)&Bs[brow][bkoff + 8] = *(const uint4*)(wp + 8);
    }
    __syncthreads();

    bf16x8 af[2], bfr[4];
#pragma unroll
    for (int i = 0; i < 2; ++i)
      af[i] = *(const bf16x8*)&As[wr * 32 + i * 16 + cl][ksl];
#pragma unroll
    for (int j = 0; j < 4; ++j)
      bfr[j] = *(const bf16x8*)&Bs[wc * 64 + j * 16 + cl][ksl];
#pragma unroll
    for (int i = 0; i < 2; ++i)
#pragma unroll
      for (int j = 0; j < 4; ++j)
        acc[i][j] = __builtin_amdgcn_mfma_f32_16x16x32_bf16(af[i], bfr[j], acc[i][j], 0, 0, 0);
    __syncthreads();
  }

  int rb = (l >> 4) * 4;
#pragma unroll
  for (int i = 0; i < 2; ++i)
#pragma unroll
    for (int j = 0; j < 4; ++j)
#pragma unroll
      for (int r = 0; r < 4; ++r) {
        int m = m0 + wr * 32 + i * 16 + rb + r;
        if (m < M)
          out[(size_t)m * nTot + n0 + wc * 64 + j * 16 + cl] = f2bf(acc[i][j][r]);
      }
}

// ---------------- node dots (vectorized uint4 loads) ----------------
__global__ void node_dots1(const ushort* __restrict__ xp, const float* __restrict__ att,
                           float* __restrict__ ad, float* __restrict__ as_, int N) {
  int idx = blockIdx.x * 256 + threadIdx.x;
  if (idx >= N * 8) return;
  int half = idx & 1, h = (idx >> 1) & 3, n = idx >> 3;
  const ushort* row = xp + (size_t)n * 256 + h * 64;
  const float* wv = att + h * 128 + half * 64;
  float s = 0.f;
#pragma unroll
  for (int c = 0; c < 64; c += 8) {
    uint4 v = *(const uint4*)(row + c);
    s += blo(v.x) * wv[c + 0] + bhi(v.x) * wv[c + 1]
       + blo(v.y) * wv[c + 2] + bhi(v.y) * wv[c + 3]
       + blo(v.z) * wv[c + 4] + bhi(v.z) * wv[c + 5]
       + blo(v.w) * wv[c + 6] + bhi(v.w) * wv[c + 7];
  }
  if (half == 0) ad[n * 4 + h] = s;
  else           as_[n * 4 + h] = s;
}
// hp2 layout: [N][256] = [mu(128) | lv(128)] per node
__global__ void node_dots2(const ushort* __restrict__ hp2,
                           const float* __restrict__ attmu, const float* __restrict__ attlv,
                           float* __restrict__ a4, int N) {
  int idx = blockIdx.x * 256 + threadIdx.x;
  if (idx >= N * 4) return;
  int w = idx & 3, n = idx >> 2;
  const float* at = (w < 2) ? attmu : attlv;
  const float* wv = at + ((w & 1) ? 128 : 0);
  const ushort* row = hp2 + (size_t)n * 256 + ((w < 2) ? 0 : 128);
  float s = 0.f;
#pragma unroll
  for (int c = 0; c < 128; c += 8) {
    uint4 v = *(const uint4*)(row + c);
    s += blo(v.x) * wv[c + 0] + bhi(v.x) * wv[c + 1]
       + blo(v.y) * wv[c + 2] + bhi(v.y) * wv[c + 3]
       + blo(v.z) * wv[c + 4] + bhi(v.z) * wv[c + 5]
       + blo(v.w) * wv[c + 6] + bhi(v.w) * wv[c + 7];
  }
  a4[idx] = s;
}

// -------- layer-1 fused softmax + aggregation + bias + ELU (CSR) ----------
__global__ __launch_bounds__(256) void fused_agg1(
    const int* __restrict__ row_ptr, const int* __restrict__ csr_src,
    const float* __restrict__ csr_w,
    const float* __restrict__ ad, const float* __restrict__ as_,
    const ushort* __restrict__ xp, const float* __restrict__ b1,
    float* __restrict__ hout) {
  int n = blockIdx.x;
  int t = threadIdx.x;
  int g = t >> 5;                 // edge group 0..7
  int l = t & 31;                 // lane; channels 8l..8l+7
  int h = l >> 3;
  __shared__ float red_m[8][32];
  __shared__ float red_d[8][32];
  __shared__ float red_acc[8][256];

  int lo = row_ptr[n], hi = row_ptr[n + 1];
  float adv = ad[n * 4 + h];

  float m = -1e30f;
  for (int i = lo + g; i < hi; i += 8) {
    int s = csr_src[i];
    float a = adv + as_[s * 4 + h];
    a = a >= 0.f ? a : NEG_SLOPE * a;
    m = fmaxf(m, a);
  }
  red_m[g][l] = m;
  __syncthreads();
  m = red_m[0][l];
#pragma unroll
  for (int gg = 1; gg < 8; ++gg) m = fmaxf(m, red_m[gg][l]);

  float acc[8];
#pragma unroll
  for (int j = 0; j < 8; ++j) acc[j] = 0.f;
  float dsum = 0.f;
  for (int i = lo + g; i < hi; i += 8) {
    int s = csr_src[i];
    float a = adv + as_[s * 4 + h];
    a = a >= 0.f ? a : NEG_SLOPE * a;
    float ev = expf(a - m);
    dsum += ev;
    float cw = ev * csr_w[i];
    uint4 v = *(const uint4*)(xp + (size_t)s * 256 + l * 8);
    acc[0] += cw * blo(v.x); acc[1] += cw * bhi(v.x);
    acc[2] += cw * blo(v.y); acc[3] += cw * bhi(v.y);
    acc[4] += cw * blo(v.z); acc[5] += cw * bhi(v.z);
    acc[6] += cw * blo(v.w); acc[7] += cw * bhi(v.w);
  }
  red_d[g][l] = dsum;
#pragma unroll
  for (int j = 0; j < 8; ++j) red_acc[g][l * 8 + j] = acc[j];
  __syncthreads();

  float v = 0.f;
#pragma unroll
  for (int gg = 0; gg < 8; ++gg) v += red_acc[gg][t];
  int h2 = t >> 6;
  float den = 0.f;
#pragma unroll
  for (int gg = 0; gg < 8; ++gg) den += red_d[gg][h2 << 3];
  float inv = 1.0f / (den + SEPS);
  float val = v * inv + b1[t];
  hout[(size_t)n * 256 + t] = val > 0.f ? val : expm1f(val);
}

// -------- layer-2 fused softmax + aggregation + bias (mu & lv) ------------
// hp2: [N][256] = [mu | lv]; mu/lv halves of the block gather the SAME 512B line.
__global__ __launch_bounds__(256) void fused_agg2(
    const int* __restrict__ row_ptr, const int* __restrict__ csr_src,
    const float* __restrict__ csr_w, const float* __restrict__ a4,
    const ushort* __restrict__ hp2,
    const float* __restrict__ bmu, const float* __restrict__ blv,
    float* __restrict__ out, int N) {
  int n = blockIdx.x;
  int t = threadIdx.x;
  int sl = t >> 7;                // 0 = mu, 1 = lv
  int u = t & 127;
  int g = u >> 4;                 // edge group 0..7
  int l = u & 15;                 // lane; channels 8l..8l+7
  __shared__ float red_m2[2][8];
  __shared__ float red_d2[2][8];
  __shared__ float red_acc2[2][8][128];

  int lo = row_ptr[n], hi = row_ptr[n + 1];
  float adv = a4[n * 4 + sl * 2];

  float m = -1e30f;
  for (int i = lo + g; i < hi; i += 8) {
    int s = csr_src[i];
    float a = adv + a4[s * 4 + sl * 2 + 1];
    a = a >= 0.f ? a : NEG_SLOPE * a;
    m = fmaxf(m, a);
  }
  if (l == 0) red_m2[sl][g] = m;
  __syncthreads();
  m = red_m2[sl][0];
#pragma unroll
  for (int gg = 1; gg < 8; ++gg) m = fmaxf(m, red_m2[sl][gg]);

  float acc[8];
#pragma unroll
  for (int j = 0; j < 8; ++j) acc[j] = 0.f;
  float dsum = 0.f;
  for (int i = lo + g; i < hi; i += 8) {
    int s = csr_src[i];
    float a = adv + a4[s * 4 + sl * 2 + 1];
    a = a >= 0.f ? a : NEG_SLOPE * a;
    float ev = expf(a - m);
    dsum += ev;
    float cw = ev * csr_w[i];
    uint4 v = *(const uint4*)(hp2 + (size_t)s * 256 + sl * 128 + l * 8);
    acc[0] += cw * blo(v.x); acc[1] += cw * bhi(v.x);
    acc[2] += cw * blo(v.y); acc[3] += cw * bhi(v.y);
    acc[4] += cw * blo(v.z); acc[5] += cw * bhi(v.z);
    acc[6] += cw * blo(v.w); acc[7] += cw * bhi(v.w);
  }
  if (l == 0) red_d2[sl][g] = dsum;
#pragma unroll
  for (int j = 0; j < 8; ++j) red_acc2[sl][g][l * 8 + j] = acc[j];
  __syncthreads();

  float v = 0.f;
#pragma unroll
  for (int gg = 0; gg < 8; ++gg) v += red_acc2[sl][gg][u];
  float den = 0.f;
#pragma unroll
  for (int gg = 0; gg < 8; ++gg) den += red_d2[sl][gg];
  float inv = 1.0f / (den + SEPS);
  out[(size_t)sl * N * 128 + (size_t)n * 128 + u] = v * inv + (sl ? blv[u] : bmu[u]);
}

extern "C" void kernel_launch(void* const* d_in, const int* in_sizes, int n_in,
                              void* d_out, int out_size, void* d_ws, size_t ws_size,
                              hipStream_t stream) {
  int OB = (out_size + 255) / 256;
  bool ok = (n_in == 12);
  int HID = 0, IN = 0, N = 0, LAT = 0, E = 0;
  if (ok) {
    HID = in_sizes[5];
    ok = ok && HID == 256;
    IN = HID ? in_sizes[3] / HID : 0;
    ok = ok && IN == 512 && in_sizes[3] == IN * HID;
    N = IN ? in_sizes[0] / IN : 0;
    ok = ok && N > 0 && in_sizes[0] == N * IN && (N % 4) == 0;
    LAT = in_sizes[8];
    ok = ok && LAT == 128;
    E = in_sizes[2];
    ok = ok && E > 0 && in_sizes[1] == 2 * E;
    ok = ok && in_sizes[4] == 2 * HID && in_sizes[6] == HID * LAT &&
         in_sizes[7] == 2 * LAT && in_sizes[9] == HID * LAT &&
         in_sizes[10] == 2 * LAT && in_sizes[11] == LAT &&
         out_size == 2 * N * LAT;
  }
  if (!ok) { fill_out<<<OB, 256, 0, stream>>>((float*)d_out, out_size, 2.0f); return; }

  char* p = (char*)d_ws;
  auto alloc = [&](size_t bytes) -> char* {
    char* r = p;
    p += (bytes + 255) & ~((size_t)255);
    return r;
  };
  ushort* xp_bf = (ushort*)alloc((size_t)N * HID * 2);   // later: hp2 (mu|lv)
  float*  hreg  = (float*) alloc((size_t)N * HID * 4);
  ushort* WT1b  = (ushort*)alloc((size_t)HID * IN * 2);  // [256][512] bf16 transposed
  ushort* WallT = (ushort*)alloc((size_t)2 * LAT * HID * 2); // [256][256] bf16 (mu|lv)
  float*  att1f = (float*) alloc((size_t)2 * HID * 4);
  float*  b1f   = (float*) alloc((size_t)HID * 4);
  float*  attmuf= (float*) alloc((size_t)2 * LAT * 4);
  float*  bmuf  = (float*) alloc((size_t)LAT * 4);
  float*  attlvf= (float*) alloc((size_t)2 * LAT * 4);
  float*  blvf  = (float*) alloc((size_t)LAT * 4);
  float*  ewf   = (float*) alloc((size_t)E * 4);
  float*  ad1   = (float*) alloc((size_t)N * 4 * 4);
  float*  as1   = (float*) alloc((size_t)N * 4 * 4);
  float*  a4    = (float*) alloc((size_t)N * 4 * 4);
  int*    srcc  = (int*)   alloc((size_t)E * 4);
  int*    dstc  = (int*)   alloc((size_t)E * 4);
  int*    csr_src=(int*)   alloc((size_t)E * 4);
  float*  csr_w = (float*) alloc((size_t)E * 4);
  int*    row_ptr=(int*)   alloc((size_t)(N + 1) * 4);
  int*    row_cur=(int*)   alloc((size_t)N * 4);
  int*    deg   = (int*)   alloc((size_t)N * 4);
  int*    modes = (int*)   alloc(16 * 4);

  size_t need = (size_t)(p - (char*)d_ws);
  if (need > ws_size) {
    fill_out<<<OB, 256, 0, stream>>>((float*)d_out, out_size, 3.0f);
    return;
  }

  ushort* hp2 = xp_bf;   // gemm2 writes after fused_agg1's last xp read

  // ---- detection (single launch) ----
  const int fidx[11] = {0, 2, 3, 4, 5, 6, 7, 8, 9, 10, 11};
  DetPtrs dp;
  for (int i = 0; i < 11; ++i) {
    dp.p[i] = (const uint32_t*)d_in[fidx[i]];
    dp.n[i] = in_sizes[fidx[i]];
  }
  dp.idx = (const uint32_t*)d_in[1];
  dp.idxn = 2 * E;
  detect_all<<<12, 256, 0, stream>>>(dp, modes);

  // ---- canonicalization ----
  int EB1 = (E + 255) / 256;
  canon_idx<<<EB1, 256, 0, stream>>>(d_in[1], srcc, dstc, E, N, &modes[11]);
  canon_f32<<<EB1, 256, 0, stream>>>(d_in[2], ewf, E, &modes[1]);
  WTArgs wt;
  wt.w1 = d_in[3]; wt.wmu = d_in[6]; wt.wlv = d_in[9];
  wt.wt1 = WT1b; wt.wall = WallT;
  int wtot = HID * IN + 2 * LAT * HID;
  canon_wt<<<(wtot + 255) / 256, 256, 0, stream>>>(wt, modes);
  SmallCan sc;
  sc.src[0] = d_in[4];  sc.dst[0] = att1f;  sc.n[0] = 2 * HID; sc.mi[0] = 3;
  sc.src[1] = d_in[5];  sc.dst[1] = b1f;    sc.n[1] = HID;     sc.mi[1] = 4;
  sc.src[2] = d_in[7];  sc.dst[2] = attmuf; sc.n[2] = 2 * LAT; sc.mi[2] = 6;
  sc.src[3] = d_in[8];  sc.dst[3] = bmuf;   sc.n[3] = LAT;     sc.mi[3] = 7;
  sc.src[4] = d_in[10]; sc.dst[4] = attlvf; sc.n[4] = 2 * LAT; sc.mi[4] = 9;
  sc.src[5] = d_in[11]; sc.dst[5] = blvf;   sc.n[5] = LAT;     sc.mi[5] = 10;
  canon_small<<<6, 256, 0, stream>>>(sc, modes);

  fill_i32<<<(N + 255) / 256, 256, 0, stream>>>(deg, N, 0);

  // ---- CSR build ----
  count_deg<<<EB1, 256, 0, stream>>>(dstc, deg, E);
  scan_deg<<<1, 1024, 0, stream>>>(deg, row_ptr, row_cur, N);
  scatter_edges<<<EB1, 256, 0, stream>>>(dstc, srcc, ewf, row_cur, csr_src, csr_w, E);

  dim3 g1((N + 63) / 64, HID / 128);       // 313 x 2
  dim3 g2((N + 63) / 64, (2 * LAT) / 128); // 313 x 2

  // ---- layer 1 ----
  gemm_mfma<512><<<g1, 256, 0, stream>>>(d_in[0], WT1b, xp_bf, N, HID, &modes[0]);
  node_dots1<<<(N * 8 + 255) / 256, 256, 0, stream>>>(xp_bf, att1f, ad1, as1, N);
  fused_agg1<<<N, 256, 0, stream>>>(row_ptr, csr_src, csr_w, ad1, as1,
                                    xp_bf, b1f, hreg);

  // ---- layer 2 (single MFMA GEMM for mu|lv) ----
  gemm_mfma<256><<<g2, 256, 0, stream>>>(hreg, WallT, hp2, N, 2 * LAT, nullptr);
  node_dots2<<<(N * 4 + 255) / 256, 256, 0, stream>>>(hp2, attmuf, attlvf, a4, N);
  fused_agg2<<<N, 256, 0, stream>>>(row_ptr, csr_src, csr_w, a4,
                                    hp2, bmuf, blvf,
                                    (float*)d_out, N);
}

// Round 4
// 303.772 us; speedup vs baseline: 10.5500x; 1.0905x over previous
//
#include <hip/hip_runtime.h>
#include <stdint.h>

#define NEG_SLOPE 0.2f
#define SEPS 1e-16f

typedef short bf16x8 __attribute__((ext_vector_type(8)));
typedef float f32x4 __attribute__((ext_vector_type(4)));

static __device__ __forceinline__ float bf2f(ushort u) {
  union { uint32_t i; float f; } v; v.i = ((uint32_t)u) << 16; return v.f;
}
static __device__ __forceinline__ ushort f2bf(float f) {
  uint32_t b = __float_as_uint(f);
  b += 0x7FFFu + ((b >> 16) & 1u);      // RNE
  return (ushort)(b >> 16);
}
static __device__ __forceinline__ float blo(uint32_t u) { return __uint_as_float(u << 16); }
static __device__ __forceinline__ float bhi(uint32_t u) { return __uint_as_float(u & 0xFFFF0000u); }
static __device__ __forceinline__ float ldf(const void* p, size_t i, int mode) {
  return mode ? ((const float*)p)[i] : bf2f(((const ushort*)p)[i]);
}

// ---------------- fills ----------------
__global__ void fill_out(float* __restrict__ out, int n, float v) {
  int i = blockIdx.x * 256 + threadIdx.x;
  if (i < n) out[i] = v;
}
__global__ void fill_i32(int* __restrict__ p, int n, int v) {
  int i = blockIdx.x * 256 + threadIdx.x;
  if (i < n) p[i] = v;
}

// ---------------- fused storage detectors (one launch, 12 blocks) ---------
struct DetPtrs {
  const uint32_t* p[11];
  int n[11];
  const uint32_t* idx;
  int idxn;
};
__global__ void detect_all(DetPtrs dp, int* __restrict__ modes) {
  int b = blockIdx.x;
  __shared__ int sL, sH;
  if (threadIdx.x == 0) { sL = 0; sH = 0; }
  __syncthreads();
  if (b < 11) {
    const uint32_t* w = dp.p[b];
    int elems = dp.n[b];
    int nprobe = min(2048, elems / 2);
    int cL = 0, cH = 0;
    for (int i = threadIdx.x; i < nprobe; i += 256) {
      uint32_t v = w[i];
      uint32_t eL = (v >> 7) & 0xFFu;
      uint32_t eH = (v >> 23) & 0xFFu;
      if (eL >= 90u && eL <= 128u) cL++;
      if (eH >= 90u && eH <= 128u) cH++;
    }
    atomicAdd(&sL, cL); atomicAdd(&sH, cH);
    __syncthreads();
    if (threadIdx.x == 0) {
      int m;
      if (sL * 4 >= nprobe * 3) m = 0;
      else if (sH * 4 >= nprobe) m = 1;
      else m = 0;
      modes[b] = m;
    }
  } else {
    const uint32_t* w = dp.idx;
    int nprobe = min(4096, dp.idxn);
    int c = 0;
    for (int i = threadIdx.x; i < nprobe; i += 256)
      if ((i & 1) && w[i] == 0u) c++;
    atomicAdd(&sL, c);
    __syncthreads();
    if (threadIdx.x == 0) modes[11] = (sL * 4 >= (nprobe / 2) * 3) ? 1 : 0;
  }
}

// ------- merged edge canon: idx + clamp + degree count + edge weight ------
__global__ void canon_edges(const void* __restrict__ ei, const void* __restrict__ ew,
                            int* __restrict__ srcc, int* __restrict__ dstc,
                            int* __restrict__ deg, float* __restrict__ ewf,
                            int E, int N, const int* __restrict__ modes) {
  int i = blockIdx.x * 256 + threadIdx.x;
  if (i >= E) return;
  int s, d;
  if (modes[11]) {
    s = (int)((const long long*)ei)[i];
    d = (int)((const long long*)ei)[E + i];
  } else {
    s = ((const int*)ei)[i];
    d = ((const int*)ei)[E + i];
  }
  s = min(max(s, 0), N - 1);
  d = min(max(d, 0), N - 1);
  srcc[i] = s;
  dstc[i] = d;
  atomicAdd(&deg[d], 1);
  float v = ldf(ew, i, modes[1]);
  if (!isfinite(v)) v = 0.f;
  ewf[i] = v;
}

// transposed bf16 weight canon: WT1b[256][512] from W1[512][256];
// WallT[256][256]: rows 0..127 from Wmu[256][128], rows 128..255 from Wlv.
struct WTArgs {
  const void* w1; const void* wmu; const void* wlv;
  ushort* wt1; ushort* wall;
};
__global__ void canon_wt(WTArgs a, const int* __restrict__ modes) {
  int i = blockIdx.x * 256 + threadIdx.x;
  const int NW1 = 256 * 512;
  if (i < NW1) {
    int n = i >> 9, k = i & 511;
    float v = ldf(a.w1, (size_t)k * 256 + n, modes[2]);
    if (!isfinite(v)) v = 0.f;
    a.wt1[i] = f2bf(v);
  } else {
    int j = i - NW1;
    if (j >= 256 * 256) return;
    int n = j >> 8, k = j & 255;
    float v;
    if (n < 128) v = ldf(a.wmu, (size_t)k * 128 + n, modes[5]);
    else         v = ldf(a.wlv, (size_t)k * 128 + (n - 128), modes[8]);
    if (!isfinite(v)) v = 0.f;
    a.wall[j] = f2bf(v);
  }
}
struct SmallCan { const void* src[6]; float* dst[6]; int n[6]; int mi[6]; };
__global__ void canon_small(SmallCan a, const int* __restrict__ modes) {
  int b = blockIdx.x;
  int m = modes[a.mi[b]];
  const void* s = a.src[b];
  float* d = a.dst[b];
  for (int i = threadIdx.x; i < a.n[b]; i += 256) {
    float v = ldf(s, i, m);
    if (!isfinite(v)) v = 0.f;
    d[i] = v;
  }
}

// ---------------- CSR build ----------------
__global__ __launch_bounds__(1024) void scan_deg(const int* __restrict__ deg,
                                                 int* __restrict__ row_ptr,
                                                 int* __restrict__ row_cur, int N) {
  __shared__ int part[1024];
  int t = threadIdx.x;
  int chunk = (N + 1023) / 1024;
  int lo = t * chunk, hi = min(lo + chunk, N);
  int s = 0;
  for (int i = lo; i < hi; ++i) s += deg[i];
  part[t] = s;
  __syncthreads();
  for (int off = 1; off < 1024; off <<= 1) {
    int v = (t >= off) ? part[t - off] : 0;
    __syncthreads();
    part[t] += v;
    __syncthreads();
  }
  int base = (t == 0) ? 0 : part[t - 1];
  for (int i = lo; i < hi; ++i) {
    row_ptr[i] = base; row_cur[i] = base;
    base += deg[i];
  }
  if (t == 1023) row_ptr[N] = part[1023];
}
__global__ void scatter_edges(const int* __restrict__ dstv, const int* __restrict__ srcv,
                              const float* __restrict__ ew, int* __restrict__ row_cur,
                              int* __restrict__ csr_src, float* __restrict__ csr_w, int E) {
  int e = blockIdx.x * 256 + threadIdx.x;
  if (e < E) {
    int p = atomicAdd(&row_cur[dstv[e]], 1);
    csr_src[p] = srcv[e];
    csr_w[p] = ew[e];
  }
}

// ---------------- MFMA GEMM: out_bf16[M][nTot] = A[M][K] @ WT^T ----------
template <int KTOT>
__global__ __launch_bounds__(256) void gemm_mfma(
    const void* __restrict__ A, const ushort* __restrict__ WT,
    ushort* __restrict__ out, int M, int nTot,
    const int* __restrict__ modeA) {
  __shared__ ushort As[64][40];    // 80B row pitch: 2-way bank alias (free)
  __shared__ ushort Bs[128][40];

  int t = threadIdx.x;
  int m0 = blockIdx.x * 64;
  int n0 = blockIdx.y * 128;
  int wid = t >> 6, l = t & 63;
  int wr = wid >> 1, wc = wid & 1;
  int mode = modeA ? *modeA : 1;

  int arow = t >> 2;               // 0..63
  int akoff = (t & 3) * 8;         // k offset in tile
  int srow = min(m0 + arow, M - 1);
  int brow = t >> 1;               // 0..127
  int bkoff = (t & 1) * 16;

  f32x4 acc[2][4];
#pragma unroll
  for (int i = 0; i < 2; ++i)
#pragma unroll
    for (int j = 0; j < 4; ++j) acc[i][j] = (f32x4){0.f, 0.f, 0.f, 0.f};

  int cl = l & 15;
  int ksl = (l >> 4) * 8;

  for (int k0 = 0; k0 < KTOT; k0 += 32) {
    if (mode) {
      const float* Af = (const float*)A + (size_t)srow * KTOT + k0 + akoff;
      float4 v0 = *(const float4*)Af;
      float4 v1 = *(const float4*)(Af + 4);
      uint4 pk;
      pk.x = (uint32_t)f2bf(v0.x) | ((uint32_t)f2bf(v0.y) << 16);
      pk.y = (uint32_t)f2bf(v0.z) | ((uint32_t)f2bf(v0.w) << 16);
      pk.z = (uint32_t)f2bf(v1.x) | ((uint32_t)f2bf(v1.y) << 16);
      pk.w = (uint32_t)f2bf(v1.z) | ((uint32_t)f2bf(v1.w) << 16);
      *(uint4*)&As[arow][akoff] = pk;
    } else {
      *(uint4*)&As[arow][akoff] =
          *(const uint4*)((const ushort*)A + (size_t)srow * KTOT + k0 + akoff);
    }
    {
      const ushort* wp = WT + (size_t)(n0 + brow) * KTOT + k0 + bkoff;
      *(uint4*)&Bs[brow][bkoff] = *(const uint4*)wp;
      *(uint4*)&Bs[brow][bkoff + 8] = *(const uint4*)(wp + 8);
    }
    __syncthreads();

    bf16x8 af[2], bfr[4];
#pragma unroll
    for (int i = 0; i < 2; ++i)
      af[i] = *(const bf16x8*)&As[wr * 32 + i * 16 + cl][ksl];
#pragma unroll
    for (int j = 0; j < 4; ++j)
      bfr[j] = *(const bf16x8*)&Bs[wc * 64 + j * 16 + cl][ksl];
#pragma unroll
    for (int i = 0; i < 2; ++i)
#pragma unroll
      for (int j = 0; j < 4; ++j)
        acc[i][j] = __builtin_amdgcn_mfma_f32_16x16x32_bf16(af[i], bfr[j], acc[i][j], 0, 0, 0);
    __syncthreads();
  }

  int rb = (l >> 4) * 4;
#pragma unroll
  for (int i = 0; i < 2; ++i)
#pragma unroll
    for (int j = 0; j < 4; ++j)
#pragma unroll
      for (int r = 0; r < 4; ++r) {
        int m = m0 + wr * 32 + i * 16 + rb + r;
        if (m < M)
          out[(size_t)m * nTot + n0 + wc * 64 + j * 16 + cl] = f2bf(acc[i][j][r]);
      }
}

// ---------------- node dots (vectorized uint4 loads) ----------------
__global__ void node_dots1(const ushort* __restrict__ xp, const float* __restrict__ att,
                           float* __restrict__ ad, float* __restrict__ as_, int N) {
  int idx = blockIdx.x * 256 + threadIdx.x;
  if (idx >= N * 8) return;
  int half = idx & 1, h = (idx >> 1) & 3, n = idx >> 3;
  const ushort* row = xp + (size_t)n * 256 + h * 64;
  const float* wv = att + h * 128 + half * 64;
  float s = 0.f;
#pragma unroll
  for (int c = 0; c < 64; c += 8) {
    uint4 v = *(const uint4*)(row + c);
    s += blo(v.x) * wv[c + 0] + bhi(v.x) * wv[c + 1]
       + blo(v.y) * wv[c + 2] + bhi(v.y) * wv[c + 3]
       + blo(v.z) * wv[c + 4] + bhi(v.z) * wv[c + 5]
       + blo(v.w) * wv[c + 6] + bhi(v.w) * wv[c + 7];
  }
  if (half == 0) ad[n * 4 + h] = s;
  else           as_[n * 4 + h] = s;
}
// hp2 layout: [N][256] = [mu(128) | lv(128)] per node
__global__ void node_dots2(const ushort* __restrict__ hp2,
                           const float* __restrict__ attmu, const float* __restrict__ attlv,
                           float* __restrict__ a4, int N) {
  int idx = blockIdx.x * 256 + threadIdx.x;
  if (idx >= N * 4) return;
  int w = idx & 3, n = idx >> 2;
  const float* at = (w < 2) ? attmu : attlv;
  const float* wv = at + ((w & 1) ? 128 : 0);
  const ushort* row = hp2 + (size_t)n * 256 + ((w < 2) ? 0 : 128);
  float s = 0.f;
#pragma unroll
  for (int c = 0; c < 128; c += 8) {
    uint4 v = *(const uint4*)(row + c);
    s += blo(v.x) * wv[c + 0] + bhi(v.x) * wv[c + 1]
       + blo(v.y) * wv[c + 2] + bhi(v.y) * wv[c + 3]
       + blo(v.z) * wv[c + 4] + bhi(v.z) * wv[c + 5]
       + blo(v.w) * wv[c + 6] + bhi(v.w) * wv[c + 7];
  }
  a4[idx] = s;
}

// -------- layer-1 fused softmax+agg+bias+ELU: ONE WAVE PER NODE -----------
// lane: (edge-slot es = lane>>2, head h = lane&3) for alpha work;
//       (subgroup sg = lane>>5, l = lane&31) for gather (l covers ch 8l..8l+7).
// No LDS, no barriers; all reductions via shfl.
__global__ __launch_bounds__(256) void fused_agg1_wave(
    const int* __restrict__ row_ptr, const int* __restrict__ csr_src,
    const float* __restrict__ csr_w,
    const float* __restrict__ ad, const float* __restrict__ as_,
    const ushort* __restrict__ xp, const float* __restrict__ b1,
    float* __restrict__ hout, int N) {
  int n = blockIdx.x * 4 + (threadIdx.x >> 6);
  if (n >= N) return;
  int lane = threadIdx.x & 63;
  int h = lane & 3;
  int es = lane >> 2;
  int sg = lane >> 5, l = lane & 31, hl = l >> 3;

  int lo = row_ptr[n], hi = row_ptr[n + 1];
  float adv = ad[n * 4 + h];

  // phase A: per-head max, edge-parallel (16 edges x 4 heads per pass)
  float m = -1e30f;
  for (int i = lo + es; i < hi; i += 16) {
    int s = csr_src[i];
    float a = adv + as_[s * 4 + h];
    a = a >= 0.f ? a : NEG_SLOPE * a;
    m = fmaxf(m, a);
  }
  m = fmaxf(m, __shfl_xor(m, 4));
  m = fmaxf(m, __shfl_xor(m, 8));
  m = fmaxf(m, __shfl_xor(m, 16));
  m = fmaxf(m, __shfl_xor(m, 32));

  // phase B: chunks of 16 edges; exp computed ONCE per (edge,head)
  float dsum = 0.f;
  float acc[8];
#pragma unroll
  for (int j = 0; j < 8; ++j) acc[j] = 0.f;

  for (int cb = lo; cb < hi; cb += 16) {
    int cn = min(16, hi - cb);
    float cwreg = 0.f; int sreg = 0;
    if (es < cn) {
      int i = cb + es;
      int s = csr_src[i];
      sreg = s;
      float a = adv + as_[s * 4 + h];
      a = a >= 0.f ? a : NEG_SLOPE * a;
      float ev = expf(a - m);
      dsum += ev;
      cwreg = ev * csr_w[i];
    }
    for (int el2 = 0; el2 < cn; el2 += 2) {
      int el = el2 + sg;
      int elc = min(el, cn - 1);
      float cw = __shfl(cwreg, (elc << 2) | hl);
      int s = __shfl(sreg, elc << 2);
      if (el < cn) {
        uint4 v = *(const uint4*)(xp + (size_t)s * 256 + l * 8);
        acc[0] += cw * blo(v.x); acc[1] += cw * bhi(v.x);
        acc[2] += cw * blo(v.y); acc[3] += cw * bhi(v.y);
        acc[4] += cw * blo(v.z); acc[5] += cw * bhi(v.z);
        acc[6] += cw * blo(v.w); acc[7] += cw * bhi(v.w);
      }
    }
  }

  // per-head denom reduce (over edge-slot bits)
  dsum += __shfl_xor(dsum, 4);
  dsum += __shfl_xor(dsum, 8);
  dsum += __shfl_xor(dsum, 16);
  dsum += __shfl_xor(dsum, 32);
  float den = __shfl(dsum, hl);       // lane hl has head h==hl

  // cross-subgroup accumulate reduce
#pragma unroll
  for (int j = 0; j < 8; ++j) acc[j] += __shfl_down(acc[j], 32);

  if (sg == 0) {
    float inv = 1.0f / (den + SEPS);
#pragma unroll
    for (int j = 0; j < 8; ++j) {
      float val = acc[j] * inv + b1[l * 8 + j];
      hout[(size_t)n * 256 + l * 8 + j] = val > 0.f ? val : expm1f(val);
    }
  }
}

// -------- layer-2 fused softmax+agg+bias: ONE WAVE PER (NODE, SLOT) -------
// lane: edge-parallel alpha; gather: 4 subgroups x 16 lanes (l covers 8 ch).
__global__ __launch_bounds__(256) void fused_agg2_wave(
    const int* __restrict__ row_ptr, const int* __restrict__ csr_src,
    const float* __restrict__ csr_w, const float* __restrict__ a4,
    const ushort* __restrict__ hp2,
    const float* __restrict__ bmu, const float* __restrict__ blv,
    float* __restrict__ out, int N) {
  int wid = blockIdx.x * 4 + (threadIdx.x >> 6);
  int n = wid >> 1, sl = wid & 1;
  if (n >= N) return;
  int lane = threadIdx.x & 63;
  int sg = lane >> 4, l = lane & 15;

  int lo = row_ptr[n], hi = row_ptr[n + 1];
  float adv = a4[n * 4 + sl * 2];

  float m = -1e30f;
  for (int i = lo + lane; i < hi; i += 64) {
    int s = csr_src[i];
    float a = adv + a4[s * 4 + sl * 2 + 1];
    a = a >= 0.f ? a : NEG_SLOPE * a;
    m = fmaxf(m, a);
  }
  m = fmaxf(m, __shfl_xor(m, 1));
  m = fmaxf(m, __shfl_xor(m, 2));
  m = fmaxf(m, __shfl_xor(m, 4));
  m = fmaxf(m, __shfl_xor(m, 8));
  m = fmaxf(m, __shfl_xor(m, 16));
  m = fmaxf(m, __shfl_xor(m, 32));

  float dsum = 0.f;
  float acc[8];
#pragma unroll
  for (int j = 0; j < 8; ++j) acc[j] = 0.f;

  for (int cb = lo; cb < hi; cb += 64) {
    int cn = min(64, hi - cb);
    float cwreg = 0.f; int sreg = 0;
    if (lane < cn) {
      int i = cb + lane;
      int s = csr_src[i];
      sreg = s;
      float a = adv + a4[s * 4 + sl * 2 + 1];
      a = a >= 0.f ? a : NEG_SLOPE * a;
      float ev = expf(a - m);
      dsum += ev;
      cwreg = ev * csr_w[i];
    }
    for (int el2 = 0; el2 < cn; el2 += 4) {
      int el = el2 + sg;
      int elc = min(el, cn - 1);
      float cw = __shfl(cwreg, elc);
      int s = __shfl(sreg, elc);
      if (el < cn) {
        uint4 v = *(const uint4*)(hp2 + (size_t)s * 256 + sl * 128 + l * 8);
        acc[0] += cw * blo(v.x); acc[1] += cw * bhi(v.x);
        acc[2] += cw * blo(v.y); acc[3] += cw * bhi(v.y);
        acc[4] += cw * blo(v.z); acc[5] += cw * bhi(v.z);
        acc[6] += cw * blo(v.w); acc[7] += cw * bhi(v.w);
      }
    }
  }

  dsum += __shfl_xor(dsum, 1);
  dsum += __shfl_xor(dsum, 2);
  dsum += __shfl_xor(dsum, 4);
  dsum += __shfl_xor(dsum, 8);
  dsum += __shfl_xor(dsum, 16);
  dsum += __shfl_xor(dsum, 32);

#pragma unroll
  for (int j = 0; j < 8; ++j) {
    acc[j] += __shfl_down(acc[j], 32);
    acc[j] += __shfl_down(acc[j], 16);
  }

  if (sg == 0) {
    float inv = 1.0f / (dsum + SEPS);
    const float* bb = sl ? blv : bmu;
    float* op = out + (size_t)sl * N * 128 + (size_t)n * 128 + l * 8;
#pragma unroll
    for (int j = 0; j < 8; ++j) op[j] = acc[j] * inv + bb[l * 8 + j];
  }
}

extern "C" void kernel_launch(void* const* d_in, const int* in_sizes, int n_in,
                              void* d_out, int out_size, void* d_ws, size_t ws_size,
                              hipStream_t stream) {
  int OB = (out_size + 255) / 256;
  bool ok = (n_in == 12);
  int HID = 0, IN = 0, N = 0, LAT = 0, E = 0;
  if (ok) {
    HID = in_sizes[5];
    ok = ok && HID == 256;
    IN = HID ? in_sizes[3] / HID : 0;
    ok = ok && IN == 512 && in_sizes[3] == IN * HID;
    N = IN ? in_sizes[0] / IN : 0;
    ok = ok && N > 0 && in_sizes[0] == N * IN && (N % 4) == 0;
    LAT = in_sizes[8];
    ok = ok && LAT == 128;
    E = in_sizes[2];
    ok = ok && E > 0 && in_sizes[1] == 2 * E;
    ok = ok && in_sizes[4] == 2 * HID && in_sizes[6] == HID * LAT &&
         in_sizes[7] == 2 * LAT && in_sizes[9] == HID * LAT &&
         in_sizes[10] == 2 * LAT && in_sizes[11] == LAT &&
         out_size == 2 * N * LAT;
  }
  if (!ok) { fill_out<<<OB, 256, 0, stream>>>((float*)d_out, out_size, 2.0f); return; }

  char* p = (char*)d_ws;
  auto alloc = [&](size_t bytes) -> char* {
    char* r = p;
    p += (bytes + 255) & ~((size_t)255);
    return r;
  };
  ushort* xp_bf = (ushort*)alloc((size_t)N * HID * 2);   // later: hp2 (mu|lv)
  float*  hreg  = (float*) alloc((size_t)N * HID * 4);
  ushort* WT1b  = (ushort*)alloc((size_t)HID * IN * 2);  // [256][512] bf16 transposed
  ushort* WallT = (ushort*)alloc((size_t)2 * LAT * HID * 2); // [256][256] bf16 (mu|lv)
  float*  att1f = (float*) alloc((size_t)2 * HID * 4);
  float*  b1f   = (float*) alloc((size_t)HID * 4);
  float*  attmuf= (float*) alloc((size_t)2 * LAT * 4);
  float*  bmuf  = (float*) alloc((size_t)LAT * 4);
  float*  attlvf= (float*) alloc((size_t)2 * LAT * 4);
  float*  blvf  = (float*) alloc((size_t)LAT * 4);
  float*  ewf   = (float*) alloc((size_t)E * 4);
  float*  ad1   = (float*) alloc((size_t)N * 4 * 4);
  float*  as1   = (float*) alloc((size_t)N * 4 * 4);
  float*  a4    = (float*) alloc((size_t)N * 4 * 4);
  int*    srcc  = (int*)   alloc((size_t)E * 4);
  int*    dstc  = (int*)   alloc((size_t)E * 4);
  int*    csr_src=(int*)   alloc((size_t)E * 4);
  float*  csr_w = (float*) alloc((size_t)E * 4);
  int*    row_ptr=(int*)   alloc((size_t)(N + 1) * 4);
  int*    row_cur=(int*)   alloc((size_t)N * 4);
  int*    deg   = (int*)   alloc((size_t)N * 4);
  int*    modes = (int*)   alloc(16 * 4);

  size_t need = (size_t)(p - (char*)d_ws);
  if (need > ws_size) {
    fill_out<<<OB, 256, 0, stream>>>((float*)d_out, out_size, 3.0f);
    return;
  }

  ushort* hp2 = xp_bf;   // gemm2 writes after fused_agg1's last xp read

  // ---- detection (single launch) ----
  const int fidx[11] = {0, 2, 3, 4, 5, 6, 7, 8, 9, 10, 11};
  DetPtrs dp;
  for (int i = 0; i < 11; ++i) {
    dp.p[i] = (const uint32_t*)d_in[fidx[i]];
    dp.n[i] = in_sizes[fidx[i]];
  }
  dp.idx = (const uint32_t*)d_in[1];
  dp.idxn = 2 * E;
  detect_all<<<12, 256, 0, stream>>>(dp, modes);

  // ---- canonicalization ----
  int EB1 = (E + 255) / 256;
  fill_i32<<<(N + 255) / 256, 256, 0, stream>>>(deg, N, 0);
  canon_edges<<<EB1, 256, 0, stream>>>(d_in[1], d_in[2], srcc, dstc, deg, ewf,
                                       E, N, modes);
  WTArgs wt;
  wt.w1 = d_in[3]; wt.wmu = d_in[6]; wt.wlv = d_in[9];
  wt.wt1 = WT1b; wt.wall = WallT;
  int wtot = HID * IN + 2 * LAT * HID;
  canon_wt<<<(wtot + 255) / 256, 256, 0, stream>>>(wt, modes);
  SmallCan sc;
  sc.src[0] = d_in[4];  sc.dst[0] = att1f;  sc.n[0] = 2 * HID; sc.mi[0] = 3;
  sc.src[1] = d_in[5];  sc.dst[1] = b1f;    sc.n[1] = HID;     sc.mi[1] = 4;
  sc.src[2] = d_in[7];  sc.dst[2] = attmuf; sc.n[2] = 2 * LAT; sc.mi[2] = 6;
  sc.src[3] = d_in[8];  sc.dst[3] = bmuf;   sc.n[3] = LAT;     sc.mi[3] = 7;
  sc.src[4] = d_in[10]; sc.dst[4] = attlvf; sc.n[4] = 2 * LAT; sc.mi[4] = 9;
  sc.src[5] = d_in[11]; sc.dst[5] = blvf;   sc.n[5] = LAT;     sc.mi[5] = 10;
  canon_small<<<6, 256, 0, stream>>>(sc, modes);

  // ---- CSR build ----
  scan_deg<<<1, 1024, 0, stream>>>(deg, row_ptr, row_cur, N);
  scatter_edges<<<EB1, 256, 0, stream>>>(dstc, srcc, ewf, row_cur, csr_src, csr_w, E);

  dim3 g1((N + 63) / 64, HID / 128);       // 313 x 2
  dim3 g2((N + 63) / 64, (2 * LAT) / 128); // 313 x 2

  // ---- layer 1 ----
  gemm_mfma<512><<<g1, 256, 0, stream>>>(d_in[0], WT1b, xp_bf, N, HID, &modes[0]);
  node_dots1<<<(N * 8 + 255) / 256, 256, 0, stream>>>(xp_bf, att1f, ad1, as1, N);
  fused_agg1_wave<<<(N + 3) / 4, 256, 0, stream>>>(row_ptr, csr_src, csr_w,
                                                   ad1, as1, xp_bf, b1f, hreg, N);

  // ---- layer 2 (single MFMA GEMM for mu|lv) ----
  gemm_mfma<256><<<g2, 256, 0, stream>>>(hreg, WallT, hp2, N, 2 * LAT, nullptr);
  node_dots2<<<(N * 4 + 255) / 256, 256, 0, stream>>>(hp2, attmuf, attlvf, a4, N);
  fused_agg2_wave<<<(2 * N + 3) / 4, 256, 0, stream>>>(row_ptr, csr_src, csr_w, a4,
                                                       hp2, bmuf, blvf,
                                                       (float*)d_out, N);
}

// Round 5
// 291.958 us; speedup vs baseline: 10.9769x; 1.0405x over previous
//
#include <hip/hip_runtime.h>
#include <stdint.h>

#define NEG_SLOPE 0.2f
#define SEPS 1e-16f

typedef short bf16x8 __attribute__((ext_vector_type(8)));
typedef float f32x4 __attribute__((ext_vector_type(4)));

static __device__ __forceinline__ float bf2f(ushort u) {
  union { uint32_t i; float f; } v; v.i = ((uint32_t)u) << 16; return v.f;
}
static __device__ __forceinline__ ushort f2bf(float f) {
  uint32_t b = __float_as_uint(f);
  b += 0x7FFFu + ((b >> 16) & 1u);      // RNE
  return (ushort)(b >> 16);
}
static __device__ __forceinline__ float blo(uint32_t u) { return __uint_as_float(u << 16); }
static __device__ __forceinline__ float bhi(uint32_t u) { return __uint_as_float(u & 0xFFFF0000u); }
static __device__ __forceinline__ float ldf(const void* p, size_t i, int mode) {
  return mode ? ((const float*)p)[i] : bf2f(((const ushort*)p)[i]);
}

// ---------------- fills ----------------
__global__ void fill_out(float* __restrict__ out, int n, float v) {
  int i = blockIdx.x * 256 + threadIdx.x;
  if (i < n) out[i] = v;
}

// ------- prologue: detectors (12 blocks) + deg fill + dots zero-fill ------
struct DetPtrs {
  const uint32_t* p[11];
  int n[11];
  const uint32_t* idx;
  int idxn;
};
__global__ void prologue(DetPtrs dp, int* __restrict__ modes,
                         int* __restrict__ deg, float* __restrict__ dots,
                         int N, int nbDeg) {
  int b = blockIdx.x;
  if (b >= 12) {
    int rb = b - 12;
    if (rb < nbDeg) {
      int i = rb * 256 + threadIdx.x;
      if (i < N) deg[i] = 0;
    } else {
      int i = (rb - nbDeg) * 256 + threadIdx.x;
      if (i < N * 12) dots[i] = 0.f;
    }
    return;
  }
  __shared__ int sL, sH;
  if (threadIdx.x == 0) { sL = 0; sH = 0; }
  __syncthreads();
  if (b < 11) {
    const uint32_t* w = dp.p[b];
    int elems = dp.n[b];
    int nprobe = min(2048, elems / 2);
    int cL = 0, cH = 0;
    for (int i = threadIdx.x; i < nprobe; i += 256) {
      uint32_t v = w[i];
      uint32_t eL = (v >> 7) & 0xFFu;
      uint32_t eH = (v >> 23) & 0xFFu;
      if (eL >= 90u && eL <= 128u) cL++;
      if (eH >= 90u && eH <= 128u) cH++;
    }
    atomicAdd(&sL, cL); atomicAdd(&sH, cH);
    __syncthreads();
    if (threadIdx.x == 0) {
      int m;
      if (sL * 4 >= nprobe * 3) m = 0;
      else if (sH * 4 >= nprobe) m = 1;
      else m = 0;
      modes[b] = m;
    }
  } else {
    const uint32_t* w = dp.idx;
    int nprobe = min(4096, dp.idxn);
    int c = 0;
    for (int i = threadIdx.x; i < nprobe; i += 256)
      if ((i & 1) && w[i] == 0u) c++;
    atomicAdd(&sL, c);
    __syncthreads();
    if (threadIdx.x == 0) modes[11] = (sL * 4 >= (nprobe / 2) * 3) ? 1 : 0;
  }
}

// ------- merged canon: edges + transposed bf16 weights + small tensors ----
struct WTArgs {
  const void* w1; const void* wmu; const void* wlv;
  ushort* wt1; ushort* wall;
};
struct SmallCan { const void* src[6]; float* dst[6]; int n[6]; int mi[6]; };
struct CanArgs {
  const void* ei; const void* ew;
  int* srcc; int* dstc; int* deg; float* ewf;
  int E; int N; int EB1; int WB;
  WTArgs wt;
  SmallCan sc;
};
__global__ void canon_all(CanArgs a, const int* __restrict__ modes) {
  int b = blockIdx.x;
  if (b < a.EB1) {
    int i = b * 256 + threadIdx.x;
    if (i >= a.E) return;
    int s, d;
    if (modes[11]) {
      s = (int)((const long long*)a.ei)[i];
      d = (int)((const long long*)a.ei)[a.E + i];
    } else {
      s = ((const int*)a.ei)[i];
      d = ((const int*)a.ei)[a.E + i];
    }
    s = min(max(s, 0), a.N - 1);
    d = min(max(d, 0), a.N - 1);
    a.srcc[i] = s;
    a.dstc[i] = d;
    atomicAdd(&a.deg[d], 1);
    float v = ldf(a.ew, i, modes[1]);
    if (!isfinite(v)) v = 0.f;
    a.ewf[i] = v;
  } else if (b < a.EB1 + a.WB) {
    int i = (b - a.EB1) * 256 + threadIdx.x;
    const int NW1 = 256 * 512;
    if (i < NW1) {
      int n = i >> 9, k = i & 511;
      float v = ldf(a.wt.w1, (size_t)k * 256 + n, modes[2]);
      if (!isfinite(v)) v = 0.f;
      a.wt.wt1[i] = f2bf(v);
    } else {
      int j = i - NW1;
      if (j >= 256 * 256) return;
      int n = j >> 8, k = j & 255;
      float v;
      if (n < 128) v = ldf(a.wt.wmu, (size_t)k * 128 + n, modes[5]);
      else         v = ldf(a.wt.wlv, (size_t)k * 128 + (n - 128), modes[8]);
      if (!isfinite(v)) v = 0.f;
      a.wt.wall[j] = f2bf(v);
    }
  } else {
    int sb = b - a.EB1 - a.WB;
    int m = modes[a.sc.mi[sb]];
    const void* s = a.sc.src[sb];
    float* d = a.sc.dst[sb];
    for (int i = threadIdx.x; i < a.sc.n[sb]; i += 256) {
      float v = ldf(s, i, m);
      if (!isfinite(v)) v = 0.f;
      d[i] = v;
    }
  }
}

// ---------------- CSR build ----------------
__global__ __launch_bounds__(1024) void scan_deg(const int* __restrict__ deg,
                                                 int* __restrict__ row_ptr,
                                                 int* __restrict__ row_cur, int N) {
  __shared__ int part[1024];
  int t = threadIdx.x;
  int chunk = (N + 1023) / 1024;
  int lo = t * chunk, hi = min(lo + chunk, N);
  int s = 0;
  for (int i = lo; i < hi; ++i) s += deg[i];
  part[t] = s;
  __syncthreads();
  for (int off = 1; off < 1024; off <<= 1) {
    int v = (t >= off) ? part[t - off] : 0;
    __syncthreads();
    part[t] += v;
    __syncthreads();
  }
  int base = (t == 0) ? 0 : part[t - 1];
  for (int i = lo; i < hi; ++i) {
    row_ptr[i] = base; row_cur[i] = base;
    base += deg[i];
  }
  if (t == 1023) row_ptr[N] = part[1023];
}
__global__ void scatter_edges(const int* __restrict__ dstv, const int* __restrict__ srcv,
                              const float* __restrict__ ew, int* __restrict__ row_cur,
                              int* __restrict__ csr_src, float* __restrict__ csr_w, int E) {
  int e = blockIdx.x * 256 + threadIdx.x;
  if (e < E) {
    int p = atomicAdd(&row_cur[dstv[e]], 1);
    csr_src[p] = srcv[e];
    csr_w[p] = ew[e];
  }
}

// ------- MFMA GEMM + fused attention-dot epilogue --------------------------
// out_bf16[M][nTot] = A[M][K] @ WT^T.  WT bf16 [nTot][K].
// Block 64x128, 4 waves 2x2, per wave 32x64 (2x4 frags 16x16), BK=32.
// DMODE 1 (layer1): heads of 64 cols; attv = att1f[h*128 + {0|64} + c];
//   dotd[m*4+h] += dot(row, att_dst), dotsrc[m*4+h] += dot(row, att_src).
// DMODE 2 (layer2): slots of 128 cols; attv = att2f[sl*256 + {0|128} + cc];
//   dotd[m*4+sl*2] += dst-dot, dotd[m*4+sl*2+1] += src-dot.
template <int KTOT, int DMODE>
__global__ __launch_bounds__(256) void gemm_mfma(
    const void* __restrict__ A, const ushort* __restrict__ WT,
    ushort* __restrict__ out, int M, int nTot,
    const int* __restrict__ modeA, const float* __restrict__ attv,
    float* __restrict__ dotd, float* __restrict__ dotsrc) {
  __shared__ ushort As[64][40];    // 80B row pitch: 2-way bank alias (free)
  __shared__ ushort Bs[128][40];

  int t = threadIdx.x;
  int m0 = blockIdx.x * 64;
  int n0 = blockIdx.y * 128;
  int wid = t >> 6, l = t & 63;
  int wr = wid >> 1, wc = wid & 1;
  int mode = modeA ? *modeA : 1;

  int arow = t >> 2;
  int akoff = (t & 3) * 8;
  int srow = min(m0 + arow, M - 1);
  int brow = t >> 1;
  int bkoff = (t & 1) * 16;

  f32x4 acc[2][4];
#pragma unroll
  for (int i = 0; i < 2; ++i)
#pragma unroll
    for (int j = 0; j < 4; ++j) acc[i][j] = (f32x4){0.f, 0.f, 0.f, 0.f};

  int cl = l & 15;
  int ksl = (l >> 4) * 8;

  for (int k0 = 0; k0 < KTOT; k0 += 32) {
    if (mode) {
      const float* Af = (const float*)A + (size_t)srow * KTOT + k0 + akoff;
      float4 v0 = *(const float4*)Af;
      float4 v1 = *(const float4*)(Af + 4);
      uint4 pk;
      pk.x = (uint32_t)f2bf(v0.x) | ((uint32_t)f2bf(v0.y) << 16);
      pk.y = (uint32_t)f2bf(v0.z) | ((uint32_t)f2bf(v0.w) << 16);
      pk.z = (uint32_t)f2bf(v1.x) | ((uint32_t)f2bf(v1.y) << 16);
      pk.w = (uint32_t)f2bf(v1.z) | ((uint32_t)f2bf(v1.w) << 16);
      *(uint4*)&As[arow][akoff] = pk;
    } else {
      *(uint4*)&As[arow][akoff] =
          *(const uint4*)((const ushort*)A + (size_t)srow * KTOT + k0 + akoff);
    }
    {
      const ushort* wp = WT + (size_t)(n0 + brow) * KTOT + k0 + bkoff;
      *(uint4*)&Bs[brow][bkoff] = *(const uint4*)wp;
      *(uint4*)&Bs[brow][bkoff + 8] = *(const uint4*)(wp + 8);
    }
    __syncthreads();

    bf16x8 af[2], bfr[4];
#pragma unroll
    for (int i = 0; i < 2; ++i)
      af[i] = *(const bf16x8*)&As[wr * 32 + i * 16 + cl][ksl];
#pragma unroll
    for (int j = 0; j < 4; ++j)
      bfr[j] = *(const bf16x8*)&Bs[wc * 64 + j * 16 + cl][ksl];
#pragma unroll
    for (int i = 0; i < 2; ++i)
#pragma unroll
      for (int j = 0; j < 4; ++j)
        acc[i][j] = __builtin_amdgcn_mfma_f32_16x16x32_bf16(af[i], bfr[j], acc[i][j], 0, 0, 0);
    __syncthreads();
  }

  int rb = (l >> 4) * 4;

  // ---- fused attention-dot epilogue ----
  if (DMODE) {
    float wd[4], ws[4];
    int hsl;
    if (DMODE == 1) {
      hsl = (n0 >> 6) + wc;          // head 0..3
#pragma unroll
      for (int j = 0; j < 4; ++j) {
        wd[j] = attv[hsl * 128 + j * 16 + cl];
        ws[j] = attv[hsl * 128 + 64 + j * 16 + cl];
      }
    } else {
      int base = n0 + wc * 64;
      hsl = base >> 7;               // slot 0..1
      int ccb = base & 127;
#pragma unroll
      for (int j = 0; j < 4; ++j) {
        wd[j] = attv[hsl * 256 + ccb + j * 16 + cl];
        ws[j] = attv[hsl * 256 + 128 + ccb + j * 16 + cl];
      }
    }
#pragma unroll
    for (int i = 0; i < 2; ++i)
#pragma unroll
      for (int r = 0; r < 4; ++r) {
        float pd = acc[i][0][r] * wd[0] + acc[i][1][r] * wd[1]
                 + acc[i][2][r] * wd[2] + acc[i][3][r] * wd[3];
        float ps = acc[i][0][r] * ws[0] + acc[i][1][r] * ws[1]
                 + acc[i][2][r] * ws[2] + acc[i][3][r] * ws[3];
        pd += __shfl_xor(pd, 1); pd += __shfl_xor(pd, 2);
        pd += __shfl_xor(pd, 4); pd += __shfl_xor(pd, 8);
        ps += __shfl_xor(ps, 1); ps += __shfl_xor(ps, 2);
        ps += __shfl_xor(ps, 4); ps += __shfl_xor(ps, 8);
        if (cl == 0) {
          int m = m0 + wr * 32 + i * 16 + rb + r;
          if (m < M) {
            if (DMODE == 1) {
              atomicAdd(&dotd[m * 4 + hsl], pd);
              atomicAdd(&dotsrc[m * 4 + hsl], ps);
            } else {
              atomicAdd(&dotd[m * 4 + hsl * 2], pd);
              atomicAdd(&dotd[m * 4 + hsl * 2 + 1], ps);
            }
          }
        }
      }
  }

#pragma unroll
  for (int i = 0; i < 2; ++i)
#pragma unroll
    for (int j = 0; j < 4; ++j)
#pragma unroll
      for (int r = 0; r < 4; ++r) {
        int m = m0 + wr * 32 + i * 16 + rb + r;
        if (m < M)
          out[(size_t)m * nTot + n0 + wc * 64 + j * 16 + cl] = f2bf(acc[i][j][r]);
      }
}

// -------- layer-1 fused: ONE WAVE PER NODE, single-pass online softmax ----
__global__ __launch_bounds__(256) void fused_agg1_wave(
    const int* __restrict__ row_ptr, const int* __restrict__ csr_src,
    const float* __restrict__ csr_w,
    const float* __restrict__ ad, const float* __restrict__ as_,
    const ushort* __restrict__ xp, const float* __restrict__ b1,
    float* __restrict__ hout, int N) {
  int n = blockIdx.x * 4 + (threadIdx.x >> 6);
  if (n >= N) return;
  int lane = threadIdx.x & 63;
  int h = lane & 3;
  int es = lane >> 2;
  int sg = lane >> 5, l = lane & 31, hl = l >> 3;

  int lo = row_ptr[n], hi = row_ptr[n + 1];
  float adv = ad[n * 4 + h];

  float m = -1e30f;
  float dsum = 0.f;
  float acc[8];
#pragma unroll
  for (int j = 0; j < 8; ++j) acc[j] = 0.f;

  for (int cb = lo; cb < hi; cb += 16) {
    int cn = min(16, hi - cb);
    float a = -1e30f;
    int sreg = 0;
    float wreg = 0.f;
    if (es < cn) {
      int i = cb + es;
      int s = csr_src[i];
      sreg = s;
      wreg = csr_w[i];
      float aa = adv + as_[s * 4 + h];
      a = aa >= 0.f ? aa : NEG_SLOPE * aa;
    }
    // per-head chunk max over es lanes
    float cm = a;
    cm = fmaxf(cm, __shfl_xor(cm, 4));
    cm = fmaxf(cm, __shfl_xor(cm, 8));
    cm = fmaxf(cm, __shfl_xor(cm, 16));
    cm = fmaxf(cm, __shfl_xor(cm, 32));
    float mnew = fmaxf(m, cm);
    float scale = expf(m - mnew);       // first chunk: exp(-inf)=0
    m = mnew;
    float ev = (es < cn) ? expf(a - m) : 0.f;
    dsum = dsum * scale + ev;
    float cwreg = ev * wreg;
    // rescale acc by this head's scale
    float sc = __shfl(scale, hl);       // lane hl: (es=0, h=hl)
#pragma unroll
    for (int j = 0; j < 8; ++j) acc[j] *= sc;
    // gather
    for (int el2 = 0; el2 < cn; el2 += 2) {
      int el = el2 + sg;
      int elc = min(el, cn - 1);
      float cw = __shfl(cwreg, (elc << 2) | hl);
      int s = __shfl(sreg, elc << 2);
      if (el < cn) {
        uint4 v = *(const uint4*)(xp + (size_t)s * 256 + l * 8);
        acc[0] += cw * blo(v.x); acc[1] += cw * bhi(v.x);
        acc[2] += cw * blo(v.y); acc[3] += cw * bhi(v.y);
        acc[4] += cw * blo(v.z); acc[5] += cw * bhi(v.z);
        acc[6] += cw * blo(v.w); acc[7] += cw * bhi(v.w);
      }
    }
  }

  dsum += __shfl_xor(dsum, 4);
  dsum += __shfl_xor(dsum, 8);
  dsum += __shfl_xor(dsum, 16);
  dsum += __shfl_xor(dsum, 32);
  float den = __shfl(dsum, hl);

#pragma unroll
  for (int j = 0; j < 8; ++j) acc[j] += __shfl_down(acc[j], 32);

  if (sg == 0) {
    float inv = 1.0f / (den + SEPS);
#pragma unroll
    for (int j = 0; j < 8; ++j) {
      float val = acc[j] * inv + b1[l * 8 + j];
      hout[(size_t)n * 256 + l * 8 + j] = val > 0.f ? val : expm1f(val);
    }
  }
}

// -------- layer-2 fused: ONE WAVE PER (NODE,SLOT), online softmax ---------
__global__ __launch_bounds__(256) void fused_agg2_wave(
    const int* __restrict__ row_ptr, const int* __restrict__ csr_src,
    const float* __restrict__ csr_w, const float* __restrict__ a4,
    const ushort* __restrict__ hp2,
    const float* __restrict__ bmu, const float* __restrict__ blv,
    float* __restrict__ out, int N) {
  int wid = blockIdx.x * 4 + (threadIdx.x >> 6);
  int n = wid >> 1, sl = wid & 1;
  if (n >= N) return;
  int lane = threadIdx.x & 63;
  int sg = lane >> 4, l = lane & 15;

  int lo = row_ptr[n], hi = row_ptr[n + 1];
  float adv = a4[n * 4 + sl * 2];

  float m = -1e30f;
  float dsum = 0.f;
  float acc[8];
#pragma unroll
  for (int j = 0; j < 8; ++j) acc[j] = 0.f;

  for (int cb = lo; cb < hi; cb += 64) {
    int cn = min(64, hi - cb);
    float a = -1e30f;
    int sreg = 0;
    float wreg = 0.f;
    if (lane < cn) {
      int i = cb + lane;
      int s = csr_src[i];
      sreg = s;
      wreg = csr_w[i];
      float aa = adv + a4[s * 4 + sl * 2 + 1];
      a = aa >= 0.f ? aa : NEG_SLOPE * aa;
    }
    float cm = a;
    cm = fmaxf(cm, __shfl_xor(cm, 1));
    cm = fmaxf(cm, __shfl_xor(cm, 2));
    cm = fmaxf(cm, __shfl_xor(cm, 4));
    cm = fmaxf(cm, __shfl_xor(cm, 8));
    cm = fmaxf(cm, __shfl_xor(cm, 16));
    cm = fmaxf(cm, __shfl_xor(cm, 32));
    float mnew = fmaxf(m, cm);
    float scale = expf(m - mnew);
    m = mnew;
    float ev = (lane < cn) ? expf(a - m) : 0.f;
    dsum = dsum * scale + ev;
    float cwreg = ev * wreg;
#pragma unroll
    for (int j = 0; j < 8; ++j) acc[j] *= scale;   // wave-uniform
    for (int el2 = 0; el2 < cn; el2 += 4) {
      int el = el2 + sg;
      int elc = min(el, cn - 1);
      float cw = __shfl(cwreg, elc);
      int s = __shfl(sreg, elc);
      if (el < cn) {
        uint4 v = *(const uint4*)(hp2 + (size_t)s * 256 + sl * 128 + l * 8);
        acc[0] += cw * blo(v.x); acc[1] += cw * bhi(v.x);
        acc[2] += cw * blo(v.y); acc[3] += cw * bhi(v.y);
        acc[4] += cw * blo(v.z); acc[5] += cw * bhi(v.z);
        acc[6] += cw * blo(v.w); acc[7] += cw * bhi(v.w);
      }
    }
  }

  dsum += __shfl_xor(dsum, 1);
  dsum += __shfl_xor(dsum, 2);
  dsum += __shfl_xor(dsum, 4);
  dsum += __shfl_xor(dsum, 8);
  dsum += __shfl_xor(dsum, 16);
  dsum += __shfl_xor(dsum, 32);

#pragma unroll
  for (int j = 0; j < 8; ++j) {
    acc[j] += __shfl_down(acc[j], 32);
    acc[j] += __shfl_down(acc[j], 16);
  }

  if (sg == 0) {
    float inv = 1.0f / (dsum + SEPS);
    const float* bb = sl ? blv : bmu;
    float* op = out + (size_t)sl * N * 128 + (size_t)n * 128 + l * 8;
#pragma unroll
    for (int j = 0; j < 8; ++j) op[j] = acc[j] * inv + bb[l * 8 + j];
  }
}

extern "C" void kernel_launch(void* const* d_in, const int* in_sizes, int n_in,
                              void* d_out, int out_size, void* d_ws, size_t ws_size,
                              hipStream_t stream) {
  int OB = (out_size + 255) / 256;
  bool ok = (n_in == 12);
  int HID = 0, IN = 0, N = 0, LAT = 0, E = 0;
  if (ok) {
    HID = in_sizes[5];
    ok = ok && HID == 256;
    IN = HID ? in_sizes[3] / HID : 0;
    ok = ok && IN == 512 && in_sizes[3] == IN * HID;
    N = IN ? in_sizes[0] / IN : 0;
    ok = ok && N > 0 && in_sizes[0] == N * IN && (N % 4) == 0;
    LAT = in_sizes[8];
    ok = ok && LAT == 128;
    E = in_sizes[2];
    ok = ok && E > 0 && in_sizes[1] == 2 * E;
    ok = ok && in_sizes[4] == 2 * HID && in_sizes[6] == HID * LAT &&
         in_sizes[7] == 2 * LAT && in_sizes[9] == HID * LAT &&
         in_sizes[10] == 2 * LAT && in_sizes[11] == LAT &&
         out_size == 2 * N * LAT;
  }
  if (!ok) { fill_out<<<OB, 256, 0, stream>>>((float*)d_out, out_size, 2.0f); return; }

  char* p = (char*)d_ws;
  auto alloc = [&](size_t bytes) -> char* {
    char* r = p;
    p += (bytes + 255) & ~((size_t)255);
    return r;
  };
  ushort* xp_bf = (ushort*)alloc((size_t)N * HID * 2);   // later: hp2 (mu|lv)
  float*  hreg  = (float*) alloc((size_t)N * HID * 4);
  ushort* WT1b  = (ushort*)alloc((size_t)HID * IN * 2);  // [256][512] bf16 transposed
  ushort* WallT = (ushort*)alloc((size_t)2 * LAT * HID * 2); // [256][256] bf16 (mu|lv)
  float*  dots  = (float*) alloc((size_t)N * 12 * 4);    // ad1 | as1 | a4
  float*  att1f = (float*) alloc((size_t)2 * HID * 4);
  float*  att2f = (float*) alloc((size_t)4 * LAT * 4);   // attmu(256) | attlv(256)
  float*  b1f   = (float*) alloc((size_t)HID * 4);
  float*  bmuf  = (float*) alloc((size_t)LAT * 4);
  float*  blvf  = (float*) alloc((size_t)LAT * 4);
  float*  ewf   = (float*) alloc((size_t)E * 4);
  int*    srcc  = (int*)   alloc((size_t)E * 4);
  int*    dstc  = (int*)   alloc((size_t)E * 4);
  int*    csr_src=(int*)   alloc((size_t)E * 4);
  float*  csr_w = (float*) alloc((size_t)E * 4);
  int*    row_ptr=(int*)   alloc((size_t)(N + 1) * 4);
  int*    row_cur=(int*)   alloc((size_t)N * 4);
  int*    deg   = (int*)   alloc((size_t)N * 4);
  int*    modes = (int*)   alloc(16 * 4);

  size_t need = (size_t)(p - (char*)d_ws);
  if (need > ws_size) {
    fill_out<<<OB, 256, 0, stream>>>((float*)d_out, out_size, 3.0f);
    return;
  }

  ushort* hp2 = xp_bf;            // gemm2 writes after fused_agg1's last xp read
  float* ad1 = dots;
  float* as1 = dots + (size_t)N * 4;
  float* a4  = dots + (size_t)N * 8;

  // ---- prologue: detection + fills (single launch) ----
  const int fidx[11] = {0, 2, 3, 4, 5, 6, 7, 8, 9, 10, 11};
  DetPtrs dp;
  for (int i = 0; i < 11; ++i) {
    dp.p[i] = (const uint32_t*)d_in[fidx[i]];
    dp.n[i] = in_sizes[fidx[i]];
  }
  dp.idx = (const uint32_t*)d_in[1];
  dp.idxn = 2 * E;
  int nbDeg = (N + 255) / 256;
  int nbDots = (N * 12 + 255) / 256;
  prologue<<<12 + nbDeg + nbDots, 256, 0, stream>>>(dp, modes, deg, dots, N, nbDeg);

  // ---- canonicalization (single launch) ----
  int EB1 = (E + 255) / 256;
  int WB = (HID * IN + 2 * LAT * HID + 255) / 256;
  CanArgs ca;
  ca.ei = d_in[1]; ca.ew = d_in[2];
  ca.srcc = srcc; ca.dstc = dstc; ca.deg = deg; ca.ewf = ewf;
  ca.E = E; ca.N = N; ca.EB1 = EB1; ca.WB = WB;
  ca.wt.w1 = d_in[3]; ca.wt.wmu = d_in[6]; ca.wt.wlv = d_in[9];
  ca.wt.wt1 = WT1b; ca.wt.wall = WallT;
  ca.sc.src[0] = d_in[4];  ca.sc.dst[0] = att1f;        ca.sc.n[0] = 2 * HID; ca.sc.mi[0] = 3;
  ca.sc.src[1] = d_in[5];  ca.sc.dst[1] = b1f;          ca.sc.n[1] = HID;     ca.sc.mi[1] = 4;
  ca.sc.src[2] = d_in[7];  ca.sc.dst[2] = att2f;        ca.sc.n[2] = 2 * LAT; ca.sc.mi[2] = 6;
  ca.sc.src[3] = d_in[8];  ca.sc.dst[3] = bmuf;         ca.sc.n[3] = LAT;     ca.sc.mi[3] = 7;
  ca.sc.src[4] = d_in[10]; ca.sc.dst[4] = att2f + 256;  ca.sc.n[4] = 2 * LAT; ca.sc.mi[4] = 9;
  ca.sc.src[5] = d_in[11]; ca.sc.dst[5] = blvf;         ca.sc.n[5] = LAT;     ca.sc.mi[5] = 10;
  canon_all<<<EB1 + WB + 6, 256, 0, stream>>>(ca, modes);

  // ---- CSR build ----
  scan_deg<<<1, 1024, 0, stream>>>(deg, row_ptr, row_cur, N);
  scatter_edges<<<EB1, 256, 0, stream>>>(dstc, srcc, ewf, row_cur, csr_src, csr_w, E);

  dim3 g1((N + 63) / 64, HID / 128);       // 313 x 2
  dim3 g2((N + 63) / 64, (2 * LAT) / 128); // 313 x 2

  // ---- layer 1 (GEMM + fused node dots) ----
  gemm_mfma<512, 1><<<g1, 256, 0, stream>>>(d_in[0], WT1b, xp_bf, N, HID,
                                            &modes[0], att1f, ad1, as1);
  fused_agg1_wave<<<(N + 3) / 4, 256, 0, stream>>>(row_ptr, csr_src, csr_w,
                                                   ad1, as1, xp_bf, b1f, hreg, N);

  // ---- layer 2 (single GEMM for mu|lv + fused node dots) ----
  gemm_mfma<256, 2><<<g2, 256, 0, stream>>>(hreg, WallT, hp2, N, 2 * LAT,
                                            nullptr, att2f, a4, nullptr);
  fused_agg2_wave<<<(2 * N + 3) / 4, 256, 0, stream>>>(row_ptr, csr_src, csr_w, a4,
                                                       hp2, bmuf, blvf,
                                                       (float*)d_out, N);
}

// Round 7
// 286.321 us; speedup vs baseline: 11.1930x; 1.0197x over previous
//
#include <hip/hip_runtime.h>
#include <stdint.h>

#define NEG_SLOPE 0.2f
#define SEPS 1e-16f

typedef short bf16x8 __attribute__((ext_vector_type(8)));
typedef float f32x4 __attribute__((ext_vector_type(4)));

static __device__ __forceinline__ float bf2f(ushort u) {
  union { uint32_t i; float f; } v; v.i = ((uint32_t)u) << 16; return v.f;
}
static __device__ __forceinline__ ushort f2bf(float f) {
  uint32_t b = __float_as_uint(f);
  b += 0x7FFFu + ((b >> 16) & 1u);      // RNE
  return (ushort)(b >> 16);
}
static __device__ __forceinline__ float blo(uint32_t u) { return __uint_as_float(u << 16); }
static __device__ __forceinline__ float bhi(uint32_t u) { return __uint_as_float(u & 0xFFFF0000u); }
static __device__ __forceinline__ float ldf(const void* p, size_t i, int mode) {
  return mode ? ((const float*)p)[i] : bf2f(((const ushort*)p)[i]);
}

// ---------------- fills ----------------
__global__ void fill_out(float* __restrict__ out, int n, float v) {
  int i = blockIdx.x * 256 + threadIdx.x;
  if (i < n) out[i] = v;
}

// ------- prologue: detectors (12 blocks) + deg zero-fill ------------------
struct DetPtrs {
  const uint32_t* p[11];
  int n[11];
  const uint32_t* idx;
  int idxn;
};
__global__ void prologue(DetPtrs dp, int* __restrict__ modes,
                         int* __restrict__ deg, int N) {
  int b = blockIdx.x;
  if (b >= 12) {
    int i = (b - 12) * 256 + threadIdx.x;
    if (i < N) deg[i] = 0;
    return;
  }
  __shared__ int sL, sH;
  if (threadIdx.x == 0) { sL = 0; sH = 0; }
  __syncthreads();
  if (b < 11) {
    const uint32_t* w = dp.p[b];
    int elems = dp.n[b];
    int nprobe = min(2048, elems / 2);
    int cL = 0, cH = 0;
    for (int i = threadIdx.x; i < nprobe; i += 256) {
      uint32_t v = w[i];
      uint32_t eL = (v >> 7) & 0xFFu;
      uint32_t eH = (v >> 23) & 0xFFu;
      if (eL >= 90u && eL <= 128u) cL++;
      if (eH >= 90u && eH <= 128u) cH++;
    }
    atomicAdd(&sL, cL); atomicAdd(&sH, cH);
    __syncthreads();
    if (threadIdx.x == 0) {
      int m;
      if (sL * 4 >= nprobe * 3) m = 0;
      else if (sH * 4 >= nprobe) m = 1;
      else m = 0;
      modes[b] = m;
    }
  } else {
    const uint32_t* w = dp.idx;
    int nprobe = min(4096, dp.idxn);
    int c = 0;
    for (int i = threadIdx.x; i < nprobe; i += 256)
      if ((i & 1) && w[i] == 0u) c++;
    atomicAdd(&sL, c);
    __syncthreads();
    if (threadIdx.x == 0) modes[11] = (sL * 4 >= (nprobe / 2) * 3) ? 1 : 0;
  }
}

// ------- merged canon: edges + transposed bf16 weights + small tensors ----
struct WTArgs {
  const void* w1; const void* wmu; const void* wlv;
  ushort* wt1; ushort* wall;
};
struct SmallCan { const void* src[6]; float* dst[6]; int n[6]; int mi[6]; };
struct CanArgs {
  const void* ei; const void* ew;
  int* srcc; int* dstc; int* deg; float* ewf;
  int E; int N; int EB1; int WB;
  WTArgs wt;
  SmallCan sc;
};
__global__ void canon_all(CanArgs a, const int* __restrict__ modes) {
  int b = blockIdx.x;
  if (b < a.EB1) {
    int i = b * 256 + threadIdx.x;
    if (i >= a.E) return;
    int s, d;
    if (modes[11]) {
      s = (int)((const long long*)a.ei)[i];
      d = (int)((const long long*)a.ei)[a.E + i];
    } else {
      s = ((const int*)a.ei)[i];
      d = ((const int*)a.ei)[a.E + i];
    }
    s = min(max(s, 0), a.N - 1);
    d = min(max(d, 0), a.N - 1);
    a.srcc[i] = s;
    a.dstc[i] = d;
    atomicAdd(&a.deg[d], 1);
    float v = ldf(a.ew, i, modes[1]);
    if (!isfinite(v)) v = 0.f;
    a.ewf[i] = v;
  } else if (b < a.EB1 + a.WB) {
    int i = (b - a.EB1) * 256 + threadIdx.x;
    const int NW1 = 256 * 512;
    if (i < NW1) {
      int n = i >> 9, k = i & 511;
      float v = ldf(a.wt.w1, (size_t)k * 256 + n, modes[2]);
      if (!isfinite(v)) v = 0.f;
      a.wt.wt1[i] = f2bf(v);
    } else {
      int j = i - NW1;
      if (j >= 256 * 256) return;
      int n = j >> 8, k = j & 255;
      float v;
      if (n < 128) v = ldf(a.wt.wmu, (size_t)k * 128 + n, modes[5]);
      else         v = ldf(a.wt.wlv, (size_t)k * 128 + (n - 128), modes[8]);
      if (!isfinite(v)) v = 0.f;
      a.wt.wall[j] = f2bf(v);
    }
  } else {
    int sb = b - a.EB1 - a.WB;
    int m = modes[a.sc.mi[sb]];
    const void* s = a.sc.src[sb];
    float* d = a.sc.dst[sb];
    for (int i = threadIdx.x; i < a.sc.n[sb]; i += 256) {
      float v = ldf(s, i, m);
      if (!isfinite(v)) v = 0.f;
      d[i] = v;
    }
  }
}

// ---------------- CSR build ----------------
__global__ __launch_bounds__(1024) void scan_deg(const int* __restrict__ deg,
                                                 int* __restrict__ row_ptr,
                                                 int* __restrict__ row_cur, int N) {
  __shared__ int part[1024];
  int t = threadIdx.x;
  int chunk = (N + 1023) / 1024;
  int lo = t * chunk, hi = min(lo + chunk, N);
  int s = 0;
  for (int i = lo; i < hi; ++i) s += deg[i];
  part[t] = s;
  __syncthreads();
  for (int off = 1; off < 1024; off <<= 1) {
    int v = (t >= off) ? part[t - off] : 0;
    __syncthreads();
    part[t] += v;
    __syncthreads();
  }
  int base = (t == 0) ? 0 : part[t - 1];
  for (int i = lo; i < hi; ++i) {
    row_ptr[i] = base; row_cur[i] = base;
    base += deg[i];
  }
  if (t == 1023) row_ptr[N] = part[1023];
}
__global__ void scatter_edges(const int* __restrict__ dstv, const int* __restrict__ srcv,
                              const float* __restrict__ ew, int* __restrict__ row_cur,
                              int* __restrict__ csr_src, float* __restrict__ csr_w, int E) {
  int e = blockIdx.x * 256 + threadIdx.x;
  if (e < E) {
    int p = atomicAdd(&row_cur[dstv[e]], 1);
    csr_src[p] = srcv[e];
    csr_w[p] = ew[e];
  }
}

// ------- MFMA GEMM 64x256 single-pass + fused attention-dot epilogue ------
// out_bf16[M][256] = A[M][KTOT] @ WT^T.  WT bf16 [256][KTOT].
// 4 waves 2x2: per wave 32 rows x 128 cols (2x8 frags of 16x16), BK=32.
// A mode: runtime via modeA (1=f32, 0=bf16); nullptr -> bf16.
// DMODE 1 (layer1): heads of 64 cols -> ad1/as1 plain stores.
// DMODE 2 (layer2): slots of 128 cols -> a4 plain stores.
template <int KTOT, int DMODE>
__global__ __launch_bounds__(256) void gemm_mfma(
    const void* __restrict__ A, const ushort* __restrict__ WT,
    ushort* __restrict__ out, int M,
    const int* __restrict__ modeA, const float* __restrict__ attv,
    float* __restrict__ dotd, float* __restrict__ dotsrc) {
  __shared__ ushort As[64][40];    // 80B pitch: 2-way bank alias (free)
  __shared__ ushort Bs[256][40];

  int t = threadIdx.x;
  int m0 = blockIdx.x * 64;
  int wid = t >> 6, l = t & 63;
  int wr = wid >> 1, wc = wid & 1;
  int mode = modeA ? *modeA : 0;

  int arow = t >> 2;
  int akoff = (t & 3) * 8;
  int srow = min(m0 + arow, M - 1);

  f32x4 acc[2][8];
#pragma unroll
  for (int i = 0; i < 2; ++i)
#pragma unroll
    for (int j = 0; j < 8; ++j) acc[i][j] = (f32x4){0.f, 0.f, 0.f, 0.f};

  int cl = l & 15;
  int ksl = (l >> 4) * 8;

  for (int k0 = 0; k0 < KTOT; k0 += 32) {
    if (mode) {
      const float* Af = (const float*)A + (size_t)srow * KTOT + k0 + akoff;
      float4 v0 = *(const float4*)Af;
      float4 v1 = *(const float4*)(Af + 4);
      uint4 pk;
      pk.x = (uint32_t)f2bf(v0.x) | ((uint32_t)f2bf(v0.y) << 16);
      pk.y = (uint32_t)f2bf(v0.z) | ((uint32_t)f2bf(v0.w) << 16);
      pk.z = (uint32_t)f2bf(v1.x) | ((uint32_t)f2bf(v1.y) << 16);
      pk.w = (uint32_t)f2bf(v1.z) | ((uint32_t)f2bf(v1.w) << 16);
      *(uint4*)&As[arow][akoff] = pk;
    } else {
      *(uint4*)&As[arow][akoff] =
          *(const uint4*)((const ushort*)A + (size_t)srow * KTOT + k0 + akoff);
    }
#pragma unroll
    for (int i = 0; i < 4; ++i) {
      int f = t + i * 256;
      int row = f >> 2, koff = (f & 3) * 8;
      *(uint4*)&Bs[row][koff] = *(const uint4*)(WT + (size_t)row * KTOT + k0 + koff);
    }
    __syncthreads();

    bf16x8 af[2], bfr[8];
#pragma unroll
    for (int i = 0; i < 2; ++i)
      af[i] = *(const bf16x8*)&As[wr * 32 + i * 16 + cl][ksl];
#pragma unroll
    for (int j = 0; j < 8; ++j)
      bfr[j] = *(const bf16x8*)&Bs[wc * 128 + j * 16 + cl][ksl];
#pragma unroll
    for (int i = 0; i < 2; ++i)
#pragma unroll
      for (int j = 0; j < 8; ++j)
        acc[i][j] = __builtin_amdgcn_mfma_f32_16x16x32_bf16(af[i], bfr[j], acc[i][j], 0, 0, 0);
    __syncthreads();
  }

  int rb = (l >> 4) * 4;

  // ---- fused attention-dot epilogue (plain stores; block covers all cols) ----
  if (DMODE == 1) {
    float wdv[8], wsv[8];
#pragma unroll
    for (int j = 0; j < 8; ++j) {
      int h = wc * 2 + (j >> 2);
      int c = (j & 3) * 16 + cl;
      wdv[j] = attv[h * 128 + c];
      wsv[j] = attv[h * 128 + 64 + c];
    }
#pragma unroll
    for (int i = 0; i < 2; ++i)
#pragma unroll
      for (int r = 0; r < 4; ++r) {
        float pd0 = acc[i][0][r] * wdv[0] + acc[i][1][r] * wdv[1]
                  + acc[i][2][r] * wdv[2] + acc[i][3][r] * wdv[3];
        float ps0 = acc[i][0][r] * wsv[0] + acc[i][1][r] * wsv[1]
                  + acc[i][2][r] * wsv[2] + acc[i][3][r] * wsv[3];
        float pd1 = acc[i][4][r] * wdv[4] + acc[i][5][r] * wdv[5]
                  + acc[i][6][r] * wdv[6] + acc[i][7][r] * wdv[7];
        float ps1 = acc[i][4][r] * wsv[4] + acc[i][5][r] * wsv[5]
                  + acc[i][6][r] * wsv[6] + acc[i][7][r] * wsv[7];
#pragma unroll
        for (int d = 1; d < 16; d <<= 1) {
          pd0 += __shfl_xor(pd0, d); ps0 += __shfl_xor(ps0, d);
          pd1 += __shfl_xor(pd1, d); ps1 += __shfl_xor(ps1, d);
        }
        if (cl == 0) {
          int m = m0 + wr * 32 + i * 16 + rb + r;
          if (m < M) {
            dotd[m * 4 + wc * 2] = pd0;
            dotsrc[m * 4 + wc * 2] = ps0;
            dotd[m * 4 + wc * 2 + 1] = pd1;
            dotsrc[m * 4 + wc * 2 + 1] = ps1;
          }
        }
      }
  } else if (DMODE == 2) {
    float wdv[8], wsv[8];
#pragma unroll
    for (int j = 0; j < 8; ++j) {
      int c = j * 16 + cl;
      wdv[j] = attv[wc * 256 + c];
      wsv[j] = attv[wc * 256 + 128 + c];
    }
#pragma unroll
    for (int i = 0; i < 2; ++i)
#pragma unroll
      for (int r = 0; r < 4; ++r) {
        float pd = 0.f, ps = 0.f;
#pragma unroll
        for (int j = 0; j < 8; ++j) {
          pd += acc[i][j][r] * wdv[j];
          ps += acc[i][j][r] * wsv[j];
        }
#pragma unroll
        for (int d = 1; d < 16; d <<= 1) {
          pd += __shfl_xor(pd, d); ps += __shfl_xor(ps, d);
        }
        if (cl == 0) {
          int m = m0 + wr * 32 + i * 16 + rb + r;
          if (m < M) {
            dotd[m * 4 + wc * 2] = pd;
            dotd[m * 4 + wc * 2 + 1] = ps;
          }
        }
      }
  }

#pragma unroll
  for (int i = 0; i < 2; ++i)
#pragma unroll
    for (int j = 0; j < 8; ++j)
#pragma unroll
      for (int r = 0; r < 4; ++r) {
        int m = m0 + wr * 32 + i * 16 + rb + r;
        if (m < M)
          out[(size_t)m * 256 + wc * 128 + j * 16 + cl] = f2bf(acc[i][j][r]);
      }
}

// -------- layer-1 fused: ONE WAVE PER NODE, online softmax, bf16 out ------
__global__ __launch_bounds__(256) void fused_agg1_wave(
    const int* __restrict__ row_ptr, const int* __restrict__ csr_src,
    const float* __restrict__ csr_w,
    const float* __restrict__ ad, const float* __restrict__ as_,
    const ushort* __restrict__ xp, const float* __restrict__ b1,
    ushort* __restrict__ hout, int N) {
  int n = blockIdx.x * 4 + (threadIdx.x >> 6);
  if (n >= N) return;
  int lane = threadIdx.x & 63;
  int h = lane & 3;
  int es = lane >> 2;
  int sg = lane >> 5, l = lane & 31, hl = l >> 3;

  int lo = row_ptr[n], hi = row_ptr[n + 1];
  float adv = ad[n * 4 + h];

  float m = -1e30f;
  float dsum = 0.f;
  float acc[8];
#pragma unroll
  for (int j = 0; j < 8; ++j) acc[j] = 0.f;

  for (int cb = lo; cb < hi; cb += 16) {
    int cn = min(16, hi - cb);
    float a = -1e30f;
    int sreg = 0;
    float wreg = 0.f;
    if (es < cn) {
      int i = cb + es;
      int s = csr_src[i];
      sreg = s;
      wreg = csr_w[i];
      float aa = adv + as_[s * 4 + h];
      a = aa >= 0.f ? aa : NEG_SLOPE * aa;
    }
    float cm = a;
    cm = fmaxf(cm, __shfl_xor(cm, 4));
    cm = fmaxf(cm, __shfl_xor(cm, 8));
    cm = fmaxf(cm, __shfl_xor(cm, 16));
    cm = fmaxf(cm, __shfl_xor(cm, 32));
    float mnew = fmaxf(m, cm);
    float scale = expf(m - mnew);       // first chunk: exp(-inf)=0
    m = mnew;
    float ev = (es < cn) ? expf(a - m) : 0.f;
    dsum = dsum * scale + ev;
    float cwreg = ev * wreg;
    float sc = __shfl(scale, hl);       // lane hl: (es=0, h=hl)
#pragma unroll
    for (int j = 0; j < 8; ++j) acc[j] *= sc;
    for (int el2 = 0; el2 < cn; el2 += 2) {
      int el = el2 + sg;
      int elc = min(el, cn - 1);
      float cw = __shfl(cwreg, (elc << 2) | hl);
      int s = __shfl(sreg, elc << 2);
      if (el < cn) {
        uint4 v = *(const uint4*)(xp + (size_t)s * 256 + l * 8);
        acc[0] += cw * blo(v.x); acc[1] += cw * bhi(v.x);
        acc[2] += cw * blo(v.y); acc[3] += cw * bhi(v.y);
        acc[4] += cw * blo(v.z); acc[5] += cw * bhi(v.z);
        acc[6] += cw * blo(v.w); acc[7] += cw * bhi(v.w);
      }
    }
  }

  dsum += __shfl_xor(dsum, 4);
  dsum += __shfl_xor(dsum, 8);
  dsum += __shfl_xor(dsum, 16);
  dsum += __shfl_xor(dsum, 32);
  float den = __shfl(dsum, hl);

#pragma unroll
  for (int j = 0; j < 8; ++j) acc[j] += __shfl_down(acc[j], 32);

  if (sg == 0) {
    float inv = 1.0f / (den + SEPS);
    uint4 pk;
    uint32_t w[4];
#pragma unroll
    for (int q = 0; q < 4; ++q) {
      float v0 = acc[q * 2] * inv + b1[l * 8 + q * 2];
      float v1 = acc[q * 2 + 1] * inv + b1[l * 8 + q * 2 + 1];
      v0 = v0 > 0.f ? v0 : expm1f(v0);
      v1 = v1 > 0.f ? v1 : expm1f(v1);
      w[q] = (uint32_t)f2bf(v0) | ((uint32_t)f2bf(v1) << 16);
    }
    pk.x = w[0]; pk.y = w[1]; pk.z = w[2]; pk.w = w[3];
    *(uint4*)(hout + (size_t)n * 256 + l * 8) = pk;
  }
}

// -------- layer-2 fused: ONE WAVE PER NODE (both slots), online softmax ---
// lanes 0-31 = mu (4 ch/lane, elements lane*4 in [0,128));
// lanes 32-63 = lv (elements lane*4 in [128,256)). sl = lane>>5 matches data.
// Each gather edge: 64 lanes x 8B = exactly one 512B hp2 row.
__global__ __launch_bounds__(256) void fused_agg2_wave(
    const int* __restrict__ row_ptr, const int* __restrict__ csr_src,
    const float* __restrict__ csr_w, const float* __restrict__ a4,
    const ushort* __restrict__ hp2,
    const float* __restrict__ bmu, const float* __restrict__ blv,
    float* __restrict__ out, int N) {
  int n = blockIdx.x * 4 + (threadIdx.x >> 6);
  if (n >= N) return;
  int lane = threadIdx.x & 63;
  int e31 = lane & 31, sl = lane >> 5;

  int lo = row_ptr[n], hi = row_ptr[n + 1];
  float adv = a4[n * 4 + sl * 2];

  float m = -1e30f;
  float dsum = 0.f;
  float acc[4];
#pragma unroll
  for (int j = 0; j < 4; ++j) acc[j] = 0.f;

  for (int cb = lo; cb < hi; cb += 32) {
    int cn = min(32, hi - cb);
    float a = -1e30f;
    int sreg = 0;
    float wreg = 0.f;
    if (e31 < cn) {
      int i = cb + e31;
      int s = csr_src[i];
      sreg = s;
      wreg = csr_w[i];
      float aa = adv + a4[s * 4 + sl * 2 + 1];
      a = aa >= 0.f ? aa : NEG_SLOPE * aa;
    }
    // per-slot chunk max (xor masks 1..16 stay within each 32-lane half)
    float cm = a;
    cm = fmaxf(cm, __shfl_xor(cm, 1));
    cm = fmaxf(cm, __shfl_xor(cm, 2));
    cm = fmaxf(cm, __shfl_xor(cm, 4));
    cm = fmaxf(cm, __shfl_xor(cm, 8));
    cm = fmaxf(cm, __shfl_xor(cm, 16));
    float mnew = fmaxf(m, cm);
    float scale = expf(m - mnew);       // first chunk: exp(-inf)=0
    m = mnew;
    float ev = (e31 < cn) ? expf(a - m) : 0.f;
    dsum = dsum * scale + ev;
    float cwreg = ev * wreg;
#pragma unroll
    for (int j = 0; j < 4; ++j) acc[j] *= scale;   // uniform within slot half
    for (int el = 0; el < cn; ++el) {
      float cw = __shfl(cwreg, (sl << 5) | el);    // own half's exp-weight
      int s = __shfl(sreg, el);                    // src id (lower half holds it)
      uint2 v = *(const uint2*)(hp2 + (size_t)s * 256 + lane * 4);
      acc[0] += cw * blo(v.x); acc[1] += cw * bhi(v.x);
      acc[2] += cw * blo(v.y); acc[3] += cw * bhi(v.y);
    }
  }

  dsum += __shfl_xor(dsum, 1);
  dsum += __shfl_xor(dsum, 2);
  dsum += __shfl_xor(dsum, 4);
  dsum += __shfl_xor(dsum, 8);
  dsum += __shfl_xor(dsum, 16);

  float inv = 1.0f / (dsum + SEPS);
  const float* bb = sl ? blv : bmu;
  int c0 = e31 * 4;
  float* op = out + (size_t)sl * N * 128 + (size_t)n * 128 + c0;
#pragma unroll
  for (int j = 0; j < 4; ++j) op[j] = acc[j] * inv + bb[c0 + j];
}

extern "C" void kernel_launch(void* const* d_in, const int* in_sizes, int n_in,
                              void* d_out, int out_size, void* d_ws, size_t ws_size,
                              hipStream_t stream) {
  int OB = (out_size + 255) / 256;
  bool ok = (n_in == 12);
  int HID = 0, IN = 0, N = 0, LAT = 0, E = 0;
  if (ok) {
    HID = in_sizes[5];
    ok = ok && HID == 256;
    IN = HID ? in_sizes[3] / HID : 0;
    ok = ok && IN == 512 && in_sizes[3] == IN * HID;
    N = IN ? in_sizes[0] / IN : 0;
    ok = ok && N > 0 && in_sizes[0] == N * IN && (N % 4) == 0;
    LAT = in_sizes[8];
    ok = ok && LAT == 128;
    E = in_sizes[2];
    ok = ok && E > 0 && in_sizes[1] == 2 * E;
    ok = ok && in_sizes[4] == 2 * HID && in_sizes[6] == HID * LAT &&
         in_sizes[7] == 2 * LAT && in_sizes[9] == HID * LAT &&
         in_sizes[10] == 2 * LAT && in_sizes[11] == LAT &&
         out_size == 2 * N * LAT;
  }
  if (!ok) { fill_out<<<OB, 256, 0, stream>>>((float*)d_out, out_size, 2.0f); return; }

  char* p = (char*)d_ws;
  auto alloc = [&](size_t bytes) -> char* {
    char* r = p;
    p += (bytes + 255) & ~((size_t)255);
    return r;
  };
  ushort* xp_bf = (ushort*)alloc((size_t)N * HID * 2);   // later: hp2 (mu|lv)
  ushort* hreg  = (ushort*)alloc((size_t)N * HID * 2);   // bf16 h (post-ELU)
  ushort* WT1b  = (ushort*)alloc((size_t)HID * IN * 2);  // [256][512] bf16 transposed
  ushort* WallT = (ushort*)alloc((size_t)2 * LAT * HID * 2); // [256][256] bf16 (mu|lv)
  float*  dots  = (float*) alloc((size_t)N * 12 * 4);    // ad1 | as1 | a4
  float*  att1f = (float*) alloc((size_t)2 * HID * 4);
  float*  att2f = (float*) alloc((size_t)4 * LAT * 4);   // attmu(256) | attlv(256)
  float*  b1f   = (float*) alloc((size_t)HID * 4);
  float*  bmuf  = (float*) alloc((size_t)LAT * 4);
  float*  blvf  = (float*) alloc((size_t)LAT * 4);
  float*  ewf   = (float*) alloc((size_t)E * 4);
  int*    srcc  = (int*)   alloc((size_t)E * 4);
  int*    dstc  = (int*)   alloc((size_t)E * 4);
  int*    csr_src=(int*)   alloc((size_t)E * 4);
  float*  csr_w = (float*) alloc((size_t)E * 4);
  int*    row_ptr=(int*)   alloc((size_t)(N + 1) * 4);
  int*    row_cur=(int*)   alloc((size_t)N * 4);
  int*    deg   = (int*)   alloc((size_t)N * 4);
  int*    modes = (int*)   alloc(16 * 4);

  size_t need = (size_t)(p - (char*)d_ws);
  if (need > ws_size) {
    fill_out<<<OB, 256, 0, stream>>>((float*)d_out, out_size, 3.0f);
    return;
  }

  ushort* hp2 = xp_bf;            // gemm2 writes after fused_agg1's last xp read
  float* ad1 = dots;
  float* as1 = dots + (size_t)N * 4;
  float* a4  = dots + (size_t)N * 8;

  // ---- prologue: detection + deg fill (single launch) ----
  const int fidx[11] = {0, 2, 3, 4, 5, 6, 7, 8, 9, 10, 11};
  DetPtrs dp;
  for (int i = 0; i < 11; ++i) {
    dp.p[i] = (const uint32_t*)d_in[fidx[i]];
    dp.n[i] = in_sizes[fidx[i]];
  }
  dp.idx = (const uint32_t*)d_in[1];
  dp.idxn = 2 * E;
  int nbDeg = (N + 255) / 256;
  prologue<<<12 + nbDeg, 256, 0, stream>>>(dp, modes, deg, N);

  // ---- canonicalization (single launch) ----
  int EB1 = (E + 255) / 256;
  int WB = (HID * IN + 2 * LAT * HID + 255) / 256;
  CanArgs ca;
  ca.ei = d_in[1]; ca.ew = d_in[2];
  ca.srcc = srcc; ca.dstc = dstc; ca.deg = deg; ca.ewf = ewf;
  ca.E = E; ca.N = N; ca.EB1 = EB1; ca.WB = WB;
  ca.wt.w1 = d_in[3]; ca.wt.wmu = d_in[6]; ca.wt.wlv = d_in[9];
  ca.wt.wt1 = WT1b; ca.wt.wall = WallT;
  ca.sc.src[0] = d_in[4];  ca.sc.dst[0] = att1f;        ca.sc.n[0] = 2 * HID; ca.sc.mi[0] = 3;
  ca.sc.src[1] = d_in[5];  ca.sc.dst[1] = b1f;          ca.sc.n[1] = HID;     ca.sc.mi[1] = 4;
  ca.sc.src[2] = d_in[7];  ca.sc.dst[2] = att2f;        ca.sc.n[2] = 2 * LAT; ca.sc.mi[2] = 6;
  ca.sc.src[3] = d_in[8];  ca.sc.dst[3] = bmuf;         ca.sc.n[3] = LAT;     ca.sc.mi[3] = 7;
  ca.sc.src[4] = d_in[10]; ca.sc.dst[4] = att2f + 256;  ca.sc.n[4] = 2 * LAT; ca.sc.mi[4] = 9;
  ca.sc.src[5] = d_in[11]; ca.sc.dst[5] = blvf;         ca.sc.n[5] = LAT;     ca.sc.mi[5] = 10;
  canon_all<<<EB1 + WB + 6, 256, 0, stream>>>(ca, modes);

  // ---- CSR build ----
  scan_deg<<<1, 1024, 0, stream>>>(deg, row_ptr, row_cur, N);
  scatter_edges<<<EB1, 256, 0, stream>>>(dstc, srcc, ewf, row_cur, csr_src, csr_w, E);

  int MB = (N + 63) / 64;

  // ---- layer 1 (GEMM 64x256 single-pass + fused node dots) ----
  gemm_mfma<512, 1><<<MB, 256, 0, stream>>>(d_in[0], WT1b, xp_bf, N,
                                            &modes[0], att1f, ad1, as1);
  fused_agg1_wave<<<(N + 3) / 4, 256, 0, stream>>>(row_ptr, csr_src, csr_w,
                                                   ad1, as1, xp_bf, b1f, hreg, N);

  // ---- layer 2 (single GEMM mu|lv, bf16 A + fused node dots) ----
  gemm_mfma<256, 2><<<MB, 256, 0, stream>>>(hreg, WallT, hp2, N,
                                            nullptr, att2f, a4, nullptr);
  fused_agg2_wave<<<(N + 3) / 4, 256, 0, stream>>>(row_ptr, csr_src, csr_w, a4,
                                                   hp2, bmuf, blvf,
                                                   (float*)d_out, N);
}

// Round 9
// 280.439 us; speedup vs baseline: 11.4278x; 1.0210x over previous
//
#include <hip/hip_runtime.h>
#include <stdint.h>

#define NEG_SLOPE 0.2f
#define SEPS 1e-16f

typedef short bf16x8 __attribute__((ext_vector_type(8)));
typedef float f32x4 __attribute__((ext_vector_type(4)));

static __device__ __forceinline__ float bf2f(ushort u) {
  union { uint32_t i; float f; } v; v.i = ((uint32_t)u) << 16; return v.f;
}
static __device__ __forceinline__ ushort f2bf(float f) {
  uint32_t b = __float_as_uint(f);
  b += 0x7FFFu + ((b >> 16) & 1u);      // RNE
  return (ushort)(b >> 16);
}
static __device__ __forceinline__ float blo(uint32_t u) { return __uint_as_float(u << 16); }
static __device__ __forceinline__ float bhi(uint32_t u) { return __uint_as_float(u & 0xFFFF0000u); }
static __device__ __forceinline__ float ldf(const void* p, size_t i, int mode) {
  return mode ? ((const float*)p)[i] : bf2f(((const ushort*)p)[i]);
}

// ---------------- fills ----------------
__global__ void fill_out(float* __restrict__ out, int n, float v) {
  int i = blockIdx.x * 256 + threadIdx.x;
  if (i < n) out[i] = v;
}

// ------- prologue: detectors (12 blocks) + deg zero-fill ------------------
struct DetPtrs {
  const uint32_t* p[11];
  int n[11];
  const uint32_t* idx;
  int idxn;
};
__global__ void prologue(DetPtrs dp, int* __restrict__ modes,
                         int* __restrict__ deg, int N) {
  int b = blockIdx.x;
  if (b >= 12) {
    int i = (b - 12) * 256 + threadIdx.x;
    if (i < N) deg[i] = 0;
    return;
  }
  __shared__ int sL, sH;
  if (threadIdx.x == 0) { sL = 0; sH = 0; }
  __syncthreads();
  if (b < 11) {
    const uint32_t* w = dp.p[b];
    int elems = dp.n[b];
    int nprobe = min(2048, elems / 2);
    int cL = 0, cH = 0;
    for (int i = threadIdx.x; i < nprobe; i += 256) {
      uint32_t v = w[i];
      uint32_t eL = (v >> 7) & 0xFFu;
      uint32_t eH = (v >> 23) & 0xFFu;
      if (eL >= 90u && eL <= 128u) cL++;
      if (eH >= 90u && eH <= 128u) cH++;
    }
    atomicAdd(&sL, cL); atomicAdd(&sH, cH);
    __syncthreads();
    if (threadIdx.x == 0) {
      int m;
      if (sL * 4 >= nprobe * 3) m = 0;
      else if (sH * 4 >= nprobe) m = 1;
      else m = 0;
      modes[b] = m;
    }
  } else {
    const uint32_t* w = dp.idx;
    int nprobe = min(4096, dp.idxn);
    int c = 0;
    for (int i = threadIdx.x; i < nprobe; i += 256)
      if ((i & 1) && w[i] == 0u) c++;
    atomicAdd(&sL, c);
    __syncthreads();
    if (threadIdx.x == 0) modes[11] = (sL * 4 >= (nprobe / 2) * 3) ? 1 : 0;
  }
}

// ------- merged canon: edges + transposed bf16 weights + small tensors ----
struct WTArgs {
  const void* w1; const void* wmu; const void* wlv;
  ushort* wt1; ushort* wall;
};
struct SmallCan { const void* src[6]; float* dst[6]; int n[6]; int mi[6]; };
struct CanArgs {
  const void* ei; const void* ew;
  int* srcc; int* dstc; int* deg; float* ewf;
  int E; int N; int EB1; int WB;
  WTArgs wt;
  SmallCan sc;
};
__global__ void canon_all(CanArgs a, const int* __restrict__ modes) {
  int b = blockIdx.x;
  if (b < a.EB1) {
    int i = b * 256 + threadIdx.x;
    if (i >= a.E) return;
    int s, d;
    if (modes[11]) {
      s = (int)((const long long*)a.ei)[i];
      d = (int)((const long long*)a.ei)[a.E + i];
    } else {
      s = ((const int*)a.ei)[i];
      d = ((const int*)a.ei)[a.E + i];
    }
    s = min(max(s, 0), a.N - 1);
    d = min(max(d, 0), a.N - 1);
    a.srcc[i] = s;
    a.dstc[i] = d;
    atomicAdd(&a.deg[d], 1);
    float v = ldf(a.ew, i, modes[1]);
    if (!isfinite(v)) v = 0.f;
    a.ewf[i] = v;
  } else if (b < a.EB1 + a.WB) {
    int i = (b - a.EB1) * 256 + threadIdx.x;
    const int NW1 = 256 * 512;
    if (i < NW1) {
      int n = i >> 9, k = i & 511;
      float v = ldf(a.wt.w1, (size_t)k * 256 + n, modes[2]);
      if (!isfinite(v)) v = 0.f;
      a.wt.wt1[i] = f2bf(v);
    } else {
      int j = i - NW1;
      if (j >= 256 * 256) return;
      int n = j >> 8, k = j & 255;
      float v;
      if (n < 128) v = ldf(a.wt.wmu, (size_t)k * 128 + n, modes[5]);
      else         v = ldf(a.wt.wlv, (size_t)k * 128 + (n - 128), modes[8]);
      if (!isfinite(v)) v = 0.f;
      a.wt.wall[j] = f2bf(v);
    }
  } else {
    int sb = b - a.EB1 - a.WB;
    int m = modes[a.sc.mi[sb]];
    const void* s = a.sc.src[sb];
    float* d = a.sc.dst[sb];
    for (int i = threadIdx.x; i < a.sc.n[sb]; i += 256) {
      float v = ldf(s, i, m);
      if (!isfinite(v)) v = 0.f;
      d[i] = v;
    }
  }
}

// ---------------- CSR scan ----------------
__global__ __launch_bounds__(1024) void scan_deg(const int* __restrict__ deg,
                                                 int* __restrict__ row_ptr,
                                                 int* __restrict__ row_cur, int N) {
  __shared__ int part[1024];
  int t = threadIdx.x;
  int chunk = (N + 1023) / 1024;
  int lo = t * chunk, hi = min(lo + chunk, N);
  int s = 0;
  for (int i = lo; i < hi; ++i) s += deg[i];
  part[t] = s;
  __syncthreads();
  for (int off = 1; off < 1024; off <<= 1) {
    int v = (t >= off) ? part[t - off] : 0;
    __syncthreads();
    part[t] += v;
    __syncthreads();
  }
  int base = (t == 0) ? 0 : part[t - 1];
  for (int i = lo; i < hi; ++i) {
    row_ptr[i] = base; row_cur[i] = base;
    base += deg[i];
  }
  if (t == 1023) row_ptr[N] = part[1023];
}

// ------- MFMA GEMM 64x256 + fused attention dots (+ optional scatter section)
// Blocks [0,SB): CSR edge scatter (independent work, merged to save a launch).
// Blocks [SB,..): out_bf16[M][256] = A[M][KTOT] @ WT^T.  WT bf16 [256][KTOT].
// 4 waves 2x2: per wave 32 rows x 128 cols (2x8 frags of 16x16), BK=32.
template <int KTOT, int DMODE>
__global__ __launch_bounds__(256) void gemm_mfma_sc(
    const void* __restrict__ A, const ushort* __restrict__ WT,
    ushort* __restrict__ out, int M,
    const int* __restrict__ modeA, const float* __restrict__ attv,
    float* __restrict__ dotd, float* __restrict__ dotsrc,
    int SB, const int* __restrict__ dstv, const int* __restrict__ srcv,
    const float* __restrict__ ew, int* __restrict__ row_cur,
    int* __restrict__ csr_src, float* __restrict__ csr_w, int E) {
  __shared__ ushort As[64][40];    // 80B pitch: 2-way bank alias (free)
  __shared__ ushort Bs[256][40];

  if ((int)blockIdx.x < SB) {      // scatter section
    int e = blockIdx.x * 256 + threadIdx.x;
    if (e < E) {
      int p = atomicAdd(&row_cur[dstv[e]], 1);
      csr_src[p] = srcv[e];
      csr_w[p] = ew[e];
    }
    return;
  }

  int t = threadIdx.x;
  int m0 = (blockIdx.x - SB) * 64;
  int wid = t >> 6, l = t & 63;
  int wr = wid >> 1, wc = wid & 1;
  int mode = modeA ? *modeA : 0;

  int arow = t >> 2;
  int akoff = (t & 3) * 8;
  int srow = min(m0 + arow, M - 1);

  f32x4 acc[2][8];
#pragma unroll
  for (int i = 0; i < 2; ++i)
#pragma unroll
    for (int j = 0; j < 8; ++j) acc[i][j] = (f32x4){0.f, 0.f, 0.f, 0.f};

  int cl = l & 15;
  int ksl = (l >> 4) * 8;

  for (int k0 = 0; k0 < KTOT; k0 += 32) {
    if (mode) {
      const float* Af = (const float*)A + (size_t)srow * KTOT + k0 + akoff;
      float4 v0 = *(const float4*)Af;
      float4 v1 = *(const float4*)(Af + 4);
      uint4 pk;
      pk.x = (uint32_t)f2bf(v0.x) | ((uint32_t)f2bf(v0.y) << 16);
      pk.y = (uint32_t)f2bf(v0.z) | ((uint32_t)f2bf(v0.w) << 16);
      pk.z = (uint32_t)f2bf(v1.x) | ((uint32_t)f2bf(v1.y) << 16);
      pk.w = (uint32_t)f2bf(v1.z) | ((uint32_t)f2bf(v1.w) << 16);
      *(uint4*)&As[arow][akoff] = pk;
    } else {
      *(uint4*)&As[arow][akoff] =
          *(const uint4*)((const ushort*)A + (size_t)srow * KTOT + k0 + akoff);
    }
#pragma unroll
    for (int i = 0; i < 4; ++i) {
      int f = t + i * 256;
      int row = f >> 2, koff = (f & 3) * 8;
      *(uint4*)&Bs[row][koff] = *(const uint4*)(WT + (size_t)row * KTOT + k0 + koff);
    }
    __syncthreads();

    bf16x8 af[2], bfr[8];
#pragma unroll
    for (int i = 0; i < 2; ++i)
      af[i] = *(const bf16x8*)&As[wr * 32 + i * 16 + cl][ksl];
#pragma unroll
    for (int j = 0; j < 8; ++j)
      bfr[j] = *(const bf16x8*)&Bs[wc * 128 + j * 16 + cl][ksl];
#pragma unroll
    for (int i = 0; i < 2; ++i)
#pragma unroll
      for (int j = 0; j < 8; ++j)
        acc[i][j] = __builtin_amdgcn_mfma_f32_16x16x32_bf16(af[i], bfr[j], acc[i][j], 0, 0, 0);
    __syncthreads();
  }

  int rb = (l >> 4) * 4;

  // ---- fused attention-dot epilogue (plain stores; block covers all cols) ----
  if (DMODE == 1) {
    float wdv[8], wsv[8];
#pragma unroll
    for (int j = 0; j < 8; ++j) {
      int h = wc * 2 + (j >> 2);
      int c = (j & 3) * 16 + cl;
      wdv[j] = attv[h * 128 + c];
      wsv[j] = attv[h * 128 + 64 + c];
    }
#pragma unroll
    for (int i = 0; i < 2; ++i)
#pragma unroll
      for (int r = 0; r < 4; ++r) {
        float pd0 = acc[i][0][r] * wdv[0] + acc[i][1][r] * wdv[1]
                  + acc[i][2][r] * wdv[2] + acc[i][3][r] * wdv[3];
        float ps0 = acc[i][0][r] * wsv[0] + acc[i][1][r] * wsv[1]
                  + acc[i][2][r] * wsv[2] + acc[i][3][r] * wsv[3];
        float pd1 = acc[i][4][r] * wdv[4] + acc[i][5][r] * wdv[5]
                  + acc[i][6][r] * wdv[6] + acc[i][7][r] * wdv[7];
        float ps1 = acc[i][4][r] * wsv[4] + acc[i][5][r] * wsv[5]
                  + acc[i][6][r] * wsv[6] + acc[i][7][r] * wsv[7];
#pragma unroll
        for (int d = 1; d < 16; d <<= 1) {
          pd0 += __shfl_xor(pd0, d); ps0 += __shfl_xor(ps0, d);
          pd1 += __shfl_xor(pd1, d); ps1 += __shfl_xor(ps1, d);
        }
        if (cl == 0) {
          int m = m0 + wr * 32 + i * 16 + rb + r;
          if (m < M) {
            dotd[m * 4 + wc * 2] = pd0;
            dotsrc[m * 4 + wc * 2] = ps0;
            dotd[m * 4 + wc * 2 + 1] = pd1;
            dotsrc[m * 4 + wc * 2 + 1] = ps1;
          }
        }
      }
  } else if (DMODE == 2) {
    float wdv[8], wsv[8];
#pragma unroll
    for (int j = 0; j < 8; ++j) {
      int c = j * 16 + cl;
      wdv[j] = attv[wc * 256 + c];
      wsv[j] = attv[wc * 256 + 128 + c];
    }
#pragma unroll
    for (int i = 0; i < 2; ++i)
#pragma unroll
      for (int r = 0; r < 4; ++r) {
        float pd = 0.f, ps = 0.f;
#pragma unroll
        for (int j = 0; j < 8; ++j) {
          pd += acc[i][j][r] * wdv[j];
          ps += acc[i][j][r] * wsv[j];
        }
#pragma unroll
        for (int d = 1; d < 16; d <<= 1) {
          pd += __shfl_xor(pd, d); ps += __shfl_xor(ps, d);
        }
        if (cl == 0) {
          int m = m0 + wr * 32 + i * 16 + rb + r;
          if (m < M) {
            dotd[m * 4 + wc * 2] = pd;
            dotd[m * 4 + wc * 2 + 1] = ps;
          }
        }
      }
  }

#pragma unroll
  for (int i = 0; i < 2; ++i)
#pragma unroll
    for (int j = 0; j < 8; ++j)
#pragma unroll
      for (int r = 0; r < 4; ++r) {
        int m = m0 + wr * 32 + i * 16 + rb + r;
        if (m < M)
          out[(size_t)m * 256 + wc * 128 + j * 16 + cl] = f2bf(acc[i][j][r]);
      }
}

// -------- layer-1 fused: ONE WAVE PER NODE, online softmax, bf16 out ------
// Gather unrolled x2: 4 uint4 loads in flight per wave (2 subgroups x 2).
__global__ __launch_bounds__(256) void fused_agg1_wave(
    const int* __restrict__ row_ptr, const int* __restrict__ csr_src,
    const float* __restrict__ csr_w,
    const float* __restrict__ ad, const float* __restrict__ as_,
    const ushort* __restrict__ xp, const float* __restrict__ b1,
    ushort* __restrict__ hout, int N) {
  int n = blockIdx.x * 4 + (threadIdx.x >> 6);
  if (n >= N) return;
  int lane = threadIdx.x & 63;
  int h = lane & 3;
  int es = lane >> 2;
  int sg = lane >> 5, l = lane & 31, hl = l >> 3;

  int lo = row_ptr[n], hi = row_ptr[n + 1];
  float adv = ad[n * 4 + h];

  float m = -1e30f;
  float dsum = 0.f;
  float acc[8];
#pragma unroll
  for (int j = 0; j < 8; ++j) acc[j] = 0.f;

  for (int cb = lo; cb < hi; cb += 16) {
    int cn = min(16, hi - cb);
    float a = -1e30f;
    int sreg = 0;
    float wreg = 0.f;
    if (es < cn) {
      int i = cb + es;
      int s = csr_src[i];
      sreg = s;
      wreg = csr_w[i];
      float aa = adv + as_[s * 4 + h];
      a = aa >= 0.f ? aa : NEG_SLOPE * aa;
    }
    float cm = a;
    cm = fmaxf(cm, __shfl_xor(cm, 4));
    cm = fmaxf(cm, __shfl_xor(cm, 8));
    cm = fmaxf(cm, __shfl_xor(cm, 16));
    cm = fmaxf(cm, __shfl_xor(cm, 32));
    float mnew = fmaxf(m, cm);
    float scale = expf(m - mnew);       // first chunk: exp(-inf)=0
    m = mnew;
    float ev = (es < cn) ? expf(a - m) : 0.f;
    dsum = dsum * scale + ev;
    float cwreg = ev * wreg;
    float sc = __shfl(scale, hl);       // lane hl: (es=0, h=hl)
#pragma unroll
    for (int j = 0; j < 8; ++j) acc[j] *= sc;
    for (int el2 = 0; el2 < cn; el2 += 4) {
      int ea = el2 + sg, eb = el2 + 2 + sg;
      int eac = min(ea, cn - 1), ebc = min(eb, cn - 1);
      float cwa = __shfl(cwreg, (eac << 2) | hl);
      int sa = __shfl(sreg, eac << 2);
      float cwb = __shfl(cwreg, (ebc << 2) | hl);
      int sb = __shfl(sreg, ebc << 2);
      bool pa = ea < cn, pb = eb < cn;
      uint4 va, vb;
      if (pa) va = *(const uint4*)(xp + (size_t)sa * 256 + l * 8);
      if (pb) vb = *(const uint4*)(xp + (size_t)sb * 256 + l * 8);
      if (pa) {
        acc[0] += cwa * blo(va.x); acc[1] += cwa * bhi(va.x);
        acc[2] += cwa * blo(va.y); acc[3] += cwa * bhi(va.y);
        acc[4] += cwa * blo(va.z); acc[5] += cwa * bhi(va.z);
        acc[6] += cwa * blo(va.w); acc[7] += cwa * bhi(va.w);
      }
      if (pb) {
        acc[0] += cwb * blo(vb.x); acc[1] += cwb * bhi(vb.x);
        acc[2] += cwb * blo(vb.y); acc[3] += cwb * bhi(vb.y);
        acc[4] += cwb * blo(vb.z); acc[5] += cwb * bhi(vb.z);
        acc[6] += cwb * blo(vb.w); acc[7] += cwb * bhi(vb.w);
      }
    }
  }

  dsum += __shfl_xor(dsum, 4);
  dsum += __shfl_xor(dsum, 8);
  dsum += __shfl_xor(dsum, 16);
  dsum += __shfl_xor(dsum, 32);
  float den = __shfl(dsum, hl);

#pragma unroll
  for (int j = 0; j < 8; ++j) acc[j] += __shfl_down(acc[j], 32);

  if (sg == 0) {
    float inv = 1.0f / (den + SEPS);
    uint4 pk;
    uint32_t w[4];
#pragma unroll
    for (int q = 0; q < 4; ++q) {
      float v0 = acc[q * 2] * inv + b1[l * 8 + q * 2];
      float v1 = acc[q * 2 + 1] * inv + b1[l * 8 + q * 2 + 1];
      v0 = v0 > 0.f ? v0 : expm1f(v0);
      v1 = v1 > 0.f ? v1 : expm1f(v1);
      w[q] = (uint32_t)f2bf(v0) | ((uint32_t)f2bf(v1) << 16);
    }
    pk.x = w[0]; pk.y = w[1]; pk.z = w[2]; pk.w = w[3];
    *(uint4*)(hout + (size_t)n * 256 + l * 8) = pk;
  }
}

// -------- layer-2 fused: ONE WAVE PER NODE, online softmax, 16B gathers ---
// Alpha phase: lanes 0-31 compute mu alphas for edges 0-31 of the chunk,
//   lanes 32-63 compute lv alphas (half = lane>>5).
// Gather: 2 subgroups of 32 lanes; subgroup reads a FULL 512B hp2 row at
//   16B/lane; lane's row-half hh = (l>>4): 0=mu ch, 1=lv ch. cw/scale/den
//   for half hh shuffled from lane hh*32. 2 edges in flight.
__global__ __launch_bounds__(256) void fused_agg2_wave(
    const int* __restrict__ row_ptr, const int* __restrict__ csr_src,
    const float* __restrict__ csr_w, const float* __restrict__ a4,
    const ushort* __restrict__ hp2,
    const float* __restrict__ bmu, const float* __restrict__ blv,
    float* __restrict__ out, int N) {
  int n = blockIdx.x * 4 + (threadIdx.x >> 6);
  if (n >= N) return;
  int lane = threadIdx.x & 63;
  int e31 = lane & 31;            // edge slot (alpha phase)
  int half = lane >> 5;           // alpha slot: 0=mu, 1=lv
  int sg = lane >> 5;             // gather subgroup
  int l = lane & 31;              // gather lane within subgroup
  int hh = l >> 4;                // row half this lane gathers (0=mu,1=lv)
  int hlane = hh << 5;            // representative lane of half hh

  int lo = row_ptr[n], hi = row_ptr[n + 1];
  float adv = a4[n * 4 + half * 2];

  float m = -1e30f;
  float dsum = 0.f;
  float acc[8];
#pragma unroll
  for (int j = 0; j < 8; ++j) acc[j] = 0.f;

  for (int cb = lo; cb < hi; cb += 32) {
    int cn = min(32, hi - cb);
    float a = -1e30f;
    int sreg = 0;
    float wreg = 0.f;
    if (e31 < cn) {
      int i = cb + e31;
      int s = csr_src[i];
      sreg = s;
      wreg = csr_w[i];
      float aa = adv + a4[s * 4 + half * 2 + 1];
      a = aa >= 0.f ? aa : NEG_SLOPE * aa;
    }
    // per-half chunk max (masks 1..16 stay within each 32-lane half)
    float cm = a;
    cm = fmaxf(cm, __shfl_xor(cm, 1));
    cm = fmaxf(cm, __shfl_xor(cm, 2));
    cm = fmaxf(cm, __shfl_xor(cm, 4));
    cm = fmaxf(cm, __shfl_xor(cm, 8));
    cm = fmaxf(cm, __shfl_xor(cm, 16));
    float mnew = fmaxf(m, cm);
    float scale = expf(m - mnew);       // first chunk: exp(-inf)=0
    m = mnew;
    float ev = (e31 < cn) ? expf(a - m) : 0.f;
    dsum = dsum * scale + ev;
    float cwreg = ev * wreg;
    float sc = __shfl(scale, hlane);    // my GATHER half's rescale
#pragma unroll
    for (int j = 0; j < 8; ++j) acc[j] *= sc;
    for (int el2 = 0; el2 < cn; el2 += 2) {
      int el = el2 + sg;
      int elc = min(el, cn - 1);
      float cw = __shfl(cwreg, elc | (hh << 5));   // half hh's weight, edge elc
      int s = __shfl(sreg, elc);                   // lanes 0-31 hold src ids
      if (el < cn) {
        uint4 v = *(const uint4*)(hp2 + (size_t)s * 256 + l * 8);
        acc[0] += cw * blo(v.x); acc[1] += cw * bhi(v.x);
        acc[2] += cw * blo(v.y); acc[3] += cw * bhi(v.y);
        acc[4] += cw * blo(v.z); acc[5] += cw * bhi(v.z);
        acc[6] += cw * blo(v.w); acc[7] += cw * bhi(v.w);
      }
    }
  }

  // per-half denom reduce
  dsum += __shfl_xor(dsum, 1);
  dsum += __shfl_xor(dsum, 2);
  dsum += __shfl_xor(dsum, 4);
  dsum += __shfl_xor(dsum, 8);
  dsum += __shfl_xor(dsum, 16);
  float den = __shfl(dsum, hlane);      // my gather half's denominator

  // cross-subgroup accumulate reduce (lane l and l+32 cover same channels)
#pragma unroll
  for (int j = 0; j < 8; ++j) acc[j] += __shfl_down(acc[j], 32);

  if (sg == 0) {
    float inv = 1.0f / (den + SEPS);
    const float* bb = hh ? blv : bmu;
    int c0 = (l & 15) * 8;
    float* op = out + (size_t)hh * N * 128 + (size_t)n * 128 + c0;
#pragma unroll
    for (int j = 0; j < 8; ++j) op[j] = acc[j] * inv + bb[c0 + j];
  }
}

extern "C" void kernel_launch(void* const* d_in, const int* in_sizes, int n_in,
                              void* d_out, int out_size, void* d_ws, size_t ws_size,
                              hipStream_t stream) {
  int OB = (out_size + 255) / 256;
  bool ok = (n_in == 12);
  int HID = 0, IN = 0, N = 0, LAT = 0, E = 0;
  if (ok) {
    HID = in_sizes[5];
    ok = ok && HID == 256;
    IN = HID ? in_sizes[3] / HID : 0;
    ok = ok && IN == 512 && in_sizes[3] == IN * HID;
    N = IN ? in_sizes[0] / IN : 0;
    ok = ok && N > 0 && in_sizes[0] == N * IN && (N % 4) == 0;
    LAT = in_sizes[8];
    ok = ok && LAT == 128;
    E = in_sizes[2];
    ok = ok && E > 0 && in_sizes[1] == 2 * E;
    ok = ok && in_sizes[4] == 2 * HID && in_sizes[6] == HID * LAT &&
         in_sizes[7] == 2 * LAT && in_sizes[9] == HID * LAT &&
         in_sizes[10] == 2 * LAT && in_sizes[11] == LAT &&
         out_size == 2 * N * LAT;
  }
  if (!ok) { fill_out<<<OB, 256, 0, stream>>>((float*)d_out, out_size, 2.0f); return; }

  char* p = (char*)d_ws;
  auto alloc = [&](size_t bytes) -> char* {
    char* r = p;
    p += (bytes + 255) & ~((size_t)255);
    return r;
  };
  ushort* xp_bf = (ushort*)alloc((size_t)N * HID * 2);   // later: hp2 (mu|lv)
  ushort* hreg  = (ushort*)alloc((size_t)N * HID * 2);   // bf16 h (post-ELU)
  ushort* WT1b  = (ushort*)alloc((size_t)HID * IN * 2);  // [256][512] bf16 transposed
  ushort* WallT = (ushort*)alloc((size_t)2 * LAT * HID * 2); // [256][256] bf16 (mu|lv)
  float*  dots  = (float*) alloc((size_t)N * 12 * 4);    // ad1 | as1 | a4
  float*  att1f = (float*) alloc((size_t)2 * HID * 4);
  float*  att2f = (float*) alloc((size_t)4 * LAT * 4);   // attmu(256) | attlv(256)
  float*  b1f   = (float*) alloc((size_t)HID * 4);
  float*  bmuf  = (float*) alloc((size_t)LAT * 4);
  float*  blvf  = (float*) alloc((size_t)LAT * 4);
  float*  ewf   = (float*) alloc((size_t)E * 4);
  int*    srcc  = (int*)   alloc((size_t)E * 4);
  int*    dstc  = (int*)   alloc((size_t)E * 4);
  int*    csr_src=(int*)   alloc((size_t)E * 4);
  float*  csr_w = (float*) alloc((size_t)E * 4);
  int*    row_ptr=(int*)   alloc((size_t)(N + 1) * 4);
  int*    row_cur=(int*)   alloc((size_t)N * 4);
  int*    deg   = (int*)   alloc((size_t)N * 4);
  int*    modes = (int*)   alloc(16 * 4);

  size_t need = (size_t)(p - (char*)d_ws);
  if (need > ws_size) {
    fill_out<<<OB, 256, 0, stream>>>((float*)d_out, out_size, 3.0f);
    return;
  }

  ushort* hp2 = xp_bf;            // gemm2 writes after fused_agg1's last xp read
  float* ad1 = dots;
  float* as1 = dots + (size_t)N * 4;
  float* a4  = dots + (size_t)N * 8;

  // ---- prologue: detection + deg fill (single launch) ----
  const int fidx[11] = {0, 2, 3, 4, 5, 6, 7, 8, 9, 10, 11};
  DetPtrs dp;
  for (int i = 0; i < 11; ++i) {
    dp.p[i] = (const uint32_t*)d_in[fidx[i]];
    dp.n[i] = in_sizes[fidx[i]];
  }
  dp.idx = (const uint32_t*)d_in[1];
  dp.idxn = 2 * E;
  int nbDeg = (N + 255) / 256;
  prologue<<<12 + nbDeg, 256, 0, stream>>>(dp, modes, deg, N);

  // ---- canonicalization (single launch) ----
  int EB1 = (E + 255) / 256;
  int WB = (HID * IN + 2 * LAT * HID + 255) / 256;
  CanArgs ca;
  ca.ei = d_in[1]; ca.ew = d_in[2];
  ca.srcc = srcc; ca.dstc = dstc; ca.deg = deg; ca.ewf = ewf;
  ca.E = E; ca.N = N; ca.EB1 = EB1; ca.WB = WB;
  ca.wt.w1 = d_in[3]; ca.wt.wmu = d_in[6]; ca.wt.wlv = d_in[9];
  ca.wt.wt1 = WT1b; ca.wt.wall = WallT;
  ca.sc.src[0] = d_in[4];  ca.sc.dst[0] = att1f;        ca.sc.n[0] = 2 * HID; ca.sc.mi[0] = 3;
  ca.sc.src[1] = d_in[5];  ca.sc.dst[1] = b1f;          ca.sc.n[1] = HID;     ca.sc.mi[1] = 4;
  ca.sc.src[2] = d_in[7];  ca.sc.dst[2] = att2f;        ca.sc.n[2] = 2 * LAT; ca.sc.mi[2] = 6;
  ca.sc.src[3] = d_in[8];  ca.sc.dst[3] = bmuf;         ca.sc.n[3] = LAT;     ca.sc.mi[3] = 7;
  ca.sc.src[4] = d_in[10]; ca.sc.dst[4] = att2f + 256;  ca.sc.n[4] = 2 * LAT; ca.sc.mi[4] = 9;
  ca.sc.src[5] = d_in[11]; ca.sc.dst[5] = blvf;         ca.sc.n[5] = LAT;     ca.sc.mi[5] = 10;
  canon_all<<<EB1 + WB + 6, 256, 0, stream>>>(ca, modes);

  // ---- CSR scan ----
  scan_deg<<<1, 1024, 0, stream>>>(deg, row_ptr, row_cur, N);

  int MB = (N + 63) / 64;

  // ---- layer 1: scatter (blocks 0..EB1) + GEMM (blocks EB1..) in ONE launch
  gemm_mfma_sc<512, 1><<<EB1 + MB, 256, 0, stream>>>(
      d_in[0], WT1b, xp_bf, N, &modes[0], att1f, ad1, as1,
      EB1, dstc, srcc, ewf, row_cur, csr_src, csr_w, E);
  fused_agg1_wave<<<(N + 3) / 4, 256, 0, stream>>>(row_ptr, csr_src, csr_w,
                                                   ad1, as1, xp_bf, b1f, hreg, N);

  // ---- layer 2 (single GEMM mu|lv, bf16 A + fused node dots) ----
  gemm_mfma_sc<256, 2><<<MB, 256, 0, stream>>>(
      hreg, WallT, hp2, N, nullptr, att2f, a4, nullptr,
      0, nullptr, nullptr, nullptr, nullptr, nullptr, nullptr, 0);
  fused_agg2_wave<<<(N + 3) / 4, 256, 0, stream>>>(row_ptr, csr_src, csr_w, a4,
                                                   hp2, bmuf, blvf,
                                                   (float*)d_out, N);
}